// Round 1
// baseline (680.548 us; speedup 1.0000x reference)
//
#include <hip/hip_runtime.h>
#include <math.h>

#define B_ 8
#define L_ 16
#define M_ 256
#define H_ 53
#define HID_ 64
#define LB_ 128  // L_*B_

// ---------------- K1: a_lin = x@Wa.T+ba ; s = x@Wg.T+bg ----------------
__global__ __launch_bounds__(64) void k1_lin(const float* __restrict__ x,
    const float* __restrict__ Wa, const float* __restrict__ ba,
    const float* __restrict__ Wg, const float* __restrict__ bg,
    float* __restrict__ a_lin, float* __restrict__ s_out) {
  int row = blockIdx.x;           // lb*256 + m
  int lb = row >> 8, m = row & 255;
  int l = lb >> 3, b = lb & 7;    // lb = l*B + b
  const float* xr = x + ((b * L_ + l) * M_ + m) * H_;
  __shared__ float xs[H_];
  int t = threadIdx.x;
  if (t < H_) xs[t] = xr[t];
  __syncthreads();
  float accA = ba[t], accS = bg[t];
  const float* wa = Wa + t * H_;
  const float* wg = Wg + t * H_;
  #pragma unroll
  for (int j = 0; j < H_; ++j) {
    float xv = xs[j];
    accA = fmaf(xv, wa[j], accA);
    accS = fmaf(xv, wg[j], accS);
  }
  a_lin[row * HID_ + t] = accA;
  s_out[row * HID_ + t] = accS;
}

// ---------------- K2: q = s@Qw ; k = s@Kw  (contract over ROW of Qw) ----------------
__global__ __launch_bounds__(64) void k2_qk(const float* __restrict__ s,
    const float* __restrict__ Qw, const float* __restrict__ Kw,
    float* __restrict__ q, float* __restrict__ k) {
  int row = blockIdx.x;
  int t = threadIdx.x;
  __shared__ float ss[HID_];
  ss[t] = s[row * HID_ + t];
  __syncthreads();
  float aq = 0.f, ak = 0.f;
  #pragma unroll
  for (int j = 0; j < HID_; ++j) {
    float sv = ss[j];
    aq = fmaf(sv, Qw[j * HID_ + t], aq);
    ak = fmaf(sv, Kw[j * HID_ + t], ak);
  }
  q[row * HID_ + t] = aq;
  k[row * HID_ + t] = ak;
}

// ---------------- K3: attention row + softmax + s_out + c_feat ----------------
__global__ __launch_bounds__(256) void k3_attn(const float* __restrict__ s,
    const float* __restrict__ q, const float* __restrict__ k,
    const int* __restrict__ Gmat,
    const float* __restrict__ W2, const float* __restrict__ b2,
    float* __restrict__ c_feat) {
  int blk = blockIdx.x;       // lb*256 + l
  int lb = blk >> 8, l = blk & 255;
  int t = threadIdx.x;
  __shared__ __align__(16) float qrow[HID_];
  __shared__ __align__(16) float srow[HID_];
  __shared__ float att[4][M_ + 4];   // padded: rows start at different banks
  __shared__ float part[4][HID_];
  __shared__ float soutl[HID_];
  __shared__ float inv_s[4];
  if (t < HID_) {
    qrow[t] = q[blk * HID_ + t];
    srow[t] = s[blk * HID_ + t];
  }
  __syncthreads();
  // phase 1: att[h][s_] = (q_row . k_row_h) * scale, masked
  {
    int s_ = t;
    const float4* krow = (const float4*)(k + (lb * M_ + s_) * HID_);
    int gm = Gmat[l * M_ + s_];
    #pragma unroll
    for (int h = 0; h < 4; ++h) {
      float d = 0.f;
      #pragma unroll
      for (int c = 0; c < 4; ++c) {
        float4 kv = krow[h * 4 + c];
        d = fmaf(qrow[h * 16 + c * 4 + 0], kv.x, d);
        d = fmaf(qrow[h * 16 + c * 4 + 1], kv.y, d);
        d = fmaf(qrow[h * 16 + c * 4 + 2], kv.z, d);
        d = fmaf(qrow[h * 16 + c * 4 + 3], kv.w, d);
      }
      att[h][s_] = (gm > 0) ? d * 0.08838834764831845f : -9e15f;
    }
  }
  __syncthreads();
  // phase 2: per-head softmax (wave w handles head w)
  {
    int h = t >> 6, lane = t & 63;
    float v0 = att[h][lane], v1 = att[h][lane + 64];
    float v2 = att[h][lane + 128], v3 = att[h][lane + 192];
    float mx = fmaxf(fmaxf(v0, v1), fmaxf(v2, v3));
    #pragma unroll
    for (int off = 32; off > 0; off >>= 1) mx = fmaxf(mx, __shfl_xor(mx, off));
    v0 = expf(v0 - mx); v1 = expf(v1 - mx); v2 = expf(v2 - mx); v3 = expf(v3 - mx);
    att[h][lane] = v0; att[h][lane + 64] = v1;
    att[h][lane + 128] = v2; att[h][lane + 192] = v3;
    float sm = v0 + v1 + v2 + v3;
    #pragma unroll
    for (int off = 32; off > 0; off >>= 1) sm += __shfl_xor(sm, off);
    if (lane == 0) inv_s[h] = 1.0f / sm;
  }
  __syncthreads();
  // phase 3: s_out partials (4 groups of 64 s_ each)
  {
    int d = t & 63, grp = t >> 6, h = d >> 4;
    const float* sp = s + (lb * M_ + grp * 64) * HID_ + d;
    float p = 0.f;
    #pragma unroll 8
    for (int ss_ = 0; ss_ < 64; ++ss_) {
      p = fmaf(att[h][grp * 64 + ss_], sp[ss_ * HID_], p);
    }
    part[grp][d] = p;
  }
  __syncthreads();
  if (t < HID_) {
    soutl[t] = (part[0][t] + part[1][t] + part[2][t] + part[3][t]) * inv_s[t >> 4];
  }
  __syncthreads();
  // phase 4: c_feat = [s, s_out] @ W2.T + b2
  if (t < HID_) {
    float acc = b2[t];
    const float* w2 = W2 + t * 2 * HID_;
    #pragma unroll
    for (int j = 0; j < HID_; ++j) acc = fmaf(srow[j], w2[j], acc);
    #pragma unroll
    for (int j = 0; j < HID_; ++j) acc = fmaf(soutl[j], w2[HID_ + j], acc);
    c_feat[blk * HID_ + t] = acc;
  }
}

// ---------------- K4: LSTM (actor blocks 0..511, critic 512..1023; 4 seqs/block) ----------------
__global__ __launch_bounds__(256) void k4_lstm(const float* __restrict__ a_lin,
    const float* __restrict__ c_feat,
    const float* __restrict__ Wih_a, const float* __restrict__ Whh_a,
    const float* __restrict__ bih_a, const float* __restrict__ bhh_a,
    const float* __restrict__ Wih_c, const float* __restrict__ Whh_c,
    const float* __restrict__ bih_c, const float* __restrict__ bhh_c,
    float* __restrict__ ah, float* __restrict__ ch) {
  int blk = blockIdx.x;
  int which = blk >> 9;
  int g = blk & 511;
  const float* xin = which ? c_feat : a_lin;
  const float* Wih = which ? Wih_c : Wih_a;
  const float* Whh = which ? Whh_c : Whh_a;
  const float* bih = which ? bih_c : bih_a;
  const float* bhh = which ? bhh_c : bhh_a;
  float* hout = which ? ch : ah;
  int t = threadIdx.x;
  int r = t;  // gate row 0..255 this thread computes (for all 4 seqs)
  // preload this thread's weight rows into registers (persist across 16 steps)
  float wih[HID_], whh[HID_];
  #pragma unroll
  for (int j = 0; j < HID_; ++j) {
    wih[j] = Wih[r * HID_ + j];
    whh[j] = Whh[r * HID_ + j];
  }
  float bsum = bih[r] + bhh[r];
  __shared__ __align__(16) float xt[4][HID_];
  __shared__ __align__(16) float hs[4][HID_];
  __shared__ float gates[4][256];
  int sq = t >> 6, kk = t & 63;
  int n = g * 4 + sq;           // sequence index = b*M + m
  int b = n >> 8, m = n & 255;
  hs[sq][kk] = 0.f;
  float cc = 0.f;
  float hlast = 0.f;
  const float* xbase = xin + (b * M_ + m) * HID_ + kk;  // +l*B*M*HID per step
  __syncthreads();
  for (int l = 0; l < L_; ++l) {
    xt[sq][kk] = xbase[l * (B_ * M_ * HID_)];
    __syncthreads();
    // gate compute: row r for 4 sequences
    float acc[4] = {bsum, bsum, bsum, bsum};
    #pragma unroll
    for (int jc = 0; jc < 16; ++jc) {
      float w0 = wih[jc * 4 + 0], w1 = wih[jc * 4 + 1];
      float w2v = wih[jc * 4 + 2], w3v = wih[jc * 4 + 3];
      float u0 = whh[jc * 4 + 0], u1 = whh[jc * 4 + 1];
      float u2v = whh[jc * 4 + 2], u3v = whh[jc * 4 + 3];
      #pragma unroll
      for (int sI = 0; sI < 4; ++sI) {
        float4 xv = ((const float4*)xt[sI])[jc];
        float4 hv = ((const float4*)hs[sI])[jc];
        acc[sI] = fmaf(w0, xv.x, acc[sI]);
        acc[sI] = fmaf(w1, xv.y, acc[sI]);
        acc[sI] = fmaf(w2v, xv.z, acc[sI]);
        acc[sI] = fmaf(w3v, xv.w, acc[sI]);
        acc[sI] = fmaf(u0, hv.x, acc[sI]);
        acc[sI] = fmaf(u1, hv.y, acc[sI]);
        acc[sI] = fmaf(u2v, hv.z, acc[sI]);
        acc[sI] = fmaf(u3v, hv.w, acc[sI]);
      }
    }
    gates[0][r] = acc[0]; gates[1][r] = acc[1];
    gates[2][r] = acc[2]; gates[3][r] = acc[3];
    __syncthreads();
    // update: thread (sq,kk) owns c/h for seq sq, hid kk
    float gi = gates[sq][kk];
    float gf = gates[sq][kk + 64];
    float gg = gates[sq][kk + 128];
    float go = gates[sq][kk + 192];
    float si = 1.f / (1.f + expf(-gi));
    float sf = 1.f / (1.f + expf(-gf));
    float so = 1.f / (1.f + expf(-go));
    cc = sf * cc + si * tanhf(gg);
    float hv = so * tanhf(cc);
    hs[sq][kk] = hv;
    hlast = hv;
    // barrier at top of next iter covers hs writes before next gate compute
  }
  hout[n * HID_ + kk] = hlast;
}

// ---------------- K5: heads + outputs ----------------
__global__ __launch_bounds__(64) void k5_heads(const float* __restrict__ ah,
    const float* __restrict__ ch, const int* __restrict__ action,
    const float* __restrict__ Wma1, const float* __restrict__ bma1,
    const float* __restrict__ Wma2, const float* __restrict__ bma2,
    const float* __restrict__ Wmc1, const float* __restrict__ bmc1,
    const float* __restrict__ Wmc2, const float* __restrict__ bmc2,
    float* __restrict__ out) {
  int n = blockIdx.x;   // b*256 + m
  int t = threadIdx.x;
  __shared__ float ha[HID_], hc[HID_], hA[HID_], logit[15], grp[6];
  ha[t] = ah[n * HID_ + t];
  hc[t] = ch[n * HID_ + t];
  __syncthreads();
  float aA = bma1[t], aC = bmc1[t];
  #pragma unroll
  for (int j = 0; j < HID_; ++j) {
    aA = fmaf(ha[j], Wma1[t * HID_ + j], aA);
    aC = fmaf(hc[j], Wmc1[t * HID_ + j], aC);
  }
  float hCt = tanhf(aC);
  hA[t] = tanhf(aA);
  __syncthreads();
  // value: wave reduce of hC[t]*Wmc2[t]
  float pv = hCt * Wmc2[t];
  #pragma unroll
  for (int off = 32; off > 0; off >>= 1) pv += __shfl_xor(pv, off);
  if (t < 15) {
    float acc = bma2[t];
    #pragma unroll
    for (int j = 0; j < HID_; ++j) acc = fmaf(hA[j], Wma2[t * HID_ + j], acc);
    logit[t] = acc;
  }
  __syncthreads();
  if (t < 3) {
    float l0 = logit[t * 5 + 0], l1 = logit[t * 5 + 1], l2 = logit[t * 5 + 2];
    float l3 = logit[t * 5 + 3], l4 = logit[t * 5 + 4];
    float mx = fmaxf(fmaxf(fmaxf(l0, l1), fmaxf(l2, l3)), l4);
    float sm = expf(l0 - mx) + expf(l1 - mx) + expf(l2 - mx) + expf(l3 - mx) + expf(l4 - mx);
    float lse = logf(sm) + mx;
    int a = action[n * 3 + t];
    float lp0 = l0 - lse, lp1 = l1 - lse, lp2 = l2 - lse, lp3 = l3 - lse, lp4 = l4 - lse;
    float lpsel = logit[t * 5 + a] - lse;
    float ent = -(expf(lp0) * lp0 + expf(lp1) * lp1 + expf(lp2) * lp2 +
                  expf(lp3) * lp3 + expf(lp4) * lp4);
    grp[t] = lpsel;
    grp[3 + t] = ent;
    out[n * 3 + t] = (float)a;          // action echoed as float
  }
  __syncthreads();
  if (t == 0) {
    out[6144 + n] = grp[0] + grp[1] + grp[2];      // lp.sum(-1)
    out[8192 + n] = grp[3] + grp[4] + grp[5];      // ent.sum(-1)
    out[10240 + n] = pv + bmc2[0];                 // value
  }
}

extern "C" void kernel_launch(void* const* d_in, const int* in_sizes, int n_in,
                              void* d_out, int out_size, void* d_ws, size_t ws_size,
                              hipStream_t stream) {
  const float* x_actor = (const float*)d_in[0];
  // d_in[1] = x_critic: reference overwrites it with x_actor -> unused
  const int* action = (const int*)d_in[2];
  const int* Gmat  = (const int*)d_in[3];
  const float* Wa = (const float*)d_in[4];  const float* ba = (const float*)d_in[5];
  const float* Wg = (const float*)d_in[6];  const float* bg = (const float*)d_in[7];
  const float* Qw = (const float*)d_in[8];  const float* Kw = (const float*)d_in[9];
  const float* W2 = (const float*)d_in[10]; const float* b2 = (const float*)d_in[11];
  const float* Wih_a = (const float*)d_in[12]; const float* Whh_a = (const float*)d_in[13];
  const float* bih_a = (const float*)d_in[14]; const float* bhh_a = (const float*)d_in[15];
  const float* Wih_c = (const float*)d_in[16]; const float* Whh_c = (const float*)d_in[17];
  const float* bih_c = (const float*)d_in[18]; const float* bhh_c = (const float*)d_in[19];
  const float* Wma1 = (const float*)d_in[20]; const float* bma1 = (const float*)d_in[21];
  const float* Wma2 = (const float*)d_in[22]; const float* bma2 = (const float*)d_in[23];
  const float* Wmc1 = (const float*)d_in[24]; const float* bmc1 = (const float*)d_in[25];
  const float* Wmc2 = (const float*)d_in[26]; const float* bmc2 = (const float*)d_in[27];

  float* ws = (float*)d_ws;
  float* a_lin = ws;                       // 128*256*64 = 2,097,152
  float* s_buf = ws + 2097152;
  float* q_buf = ws + 4194304;
  float* k_buf = ws + 6291456;
  float* cfeat = ws + 8388608;
  float* ah    = ws + 10485760;            // 2048*64
  float* ch    = ws + 10616832;
  float* out = (float*)d_out;

  k1_lin<<<LB_ * M_, 64, 0, stream>>>(x_actor, Wa, ba, Wg, bg, a_lin, s_buf);
  k2_qk<<<LB_ * M_, 64, 0, stream>>>(s_buf, Qw, Kw, q_buf, k_buf);
  k3_attn<<<LB_ * M_, 256, 0, stream>>>(s_buf, q_buf, k_buf, Gmat, W2, b2, cfeat);
  k4_lstm<<<1024, 256, 0, stream>>>(a_lin, cfeat, Wih_a, Whh_a, bih_a, bhh_a,
                                    Wih_c, Whh_c, bih_c, bhh_c, ah, ch);
  k5_heads<<<2048, 64, 0, stream>>>(ah, ch, action, Wma1, bma1, Wma2, bma2,
                                    Wmc1, bmc1, Wmc2, bmc2, out);
}

// Round 2
// 203.100 us; speedup vs baseline: 3.3508x; 3.3508x over previous
//
#include <hip/hip_runtime.h>
#include <math.h>

#define B_ 8
#define L_ 16
#define M_ 256
#define H_ 53
#define HID_ 64
#define LB_ 128  // L_*B_

typedef __attribute__((ext_vector_type(8))) short bf16x8;
typedef __attribute__((ext_vector_type(4))) float f32x4;

__device__ inline unsigned short f2bf(float f) {
  unsigned u = __builtin_bit_cast(unsigned, f);
  unsigned r = (u + 0x7FFFu + ((u >> 16) & 1u)) >> 16;
  return (unsigned short)r;
}

// ---------------- Kernel A: fused  a_lin/s (x@W.T) + q/k (s@Qw, s@Kw) ----------------
// 2048 blocks x 256 threads; block handles 16 rows (row = lb*256+m), wave handles 4.
__global__ __launch_bounds__(256) void kA_lin(const float* __restrict__ x,
    const float* __restrict__ Wa, const float* __restrict__ ba,
    const float* __restrict__ Wg, const float* __restrict__ bg,
    const float* __restrict__ Qw, const float* __restrict__ Kw,
    float* __restrict__ a_lin, unsigned short* __restrict__ s_b,
    unsigned short* __restrict__ q_b, unsigned short* __restrict__ k_b) {
  __shared__ float wa_lds[HID_ * H_];
  __shared__ float wg_lds[HID_ * H_];
  __shared__ float x_lds[16][H_];
  __shared__ float s_sh[16][HID_];
  int tid = threadIdx.x;
  int row0 = blockIdx.x * 16;
  for (int i = tid; i < HID_ * H_; i += 256) { wa_lds[i] = Wa[i]; wg_lds[i] = Wg[i]; }
  for (int i = tid; i < 16 * H_; i += 256) {
    int r = i / H_, j = i - r * H_;
    int row = row0 + r;
    int lb = row >> 8, m = row & 255;
    int l = lb >> 3, b = lb & 7;
    x_lds[r][j] = x[((b * L_ + l) * M_ + m) * H_ + j];
  }
  __syncthreads();
  int lane = tid & 63, wv = tid >> 6;
  float aA[4], aS[4];
  float bav = ba[lane], bgv = bg[lane];
  #pragma unroll
  for (int ri = 0; ri < 4; ++ri) { aA[ri] = bav; aS[ri] = bgv; }
  for (int j = 0; j < H_; ++j) {
    float wa = wa_lds[lane * H_ + j];
    float wg = wg_lds[lane * H_ + j];
    #pragma unroll
    for (int ri = 0; ri < 4; ++ri) {
      float xv = x_lds[wv * 4 + ri][j];
      aA[ri] = fmaf(xv, wa, aA[ri]);
      aS[ri] = fmaf(xv, wg, aS[ri]);
    }
  }
  #pragma unroll
  for (int ri = 0; ri < 4; ++ri) {
    int row = row0 + wv * 4 + ri;
    a_lin[row * HID_ + lane] = aA[ri];
    s_sh[wv * 4 + ri][lane] = aS[ri];
    s_b[row * HID_ + lane] = f2bf(aS[ri]);
  }
  __syncthreads();
  float aq[4] = {0.f, 0.f, 0.f, 0.f}, ak[4] = {0.f, 0.f, 0.f, 0.f};
  for (int j = 0; j < HID_; ++j) {
    float qw = Qw[j * HID_ + lane];
    float kw = Kw[j * HID_ + lane];
    #pragma unroll
    for (int ri = 0; ri < 4; ++ri) {
      float sv = s_sh[wv * 4 + ri][j];
      aq[ri] = fmaf(sv, qw, aq[ri]);
      ak[ri] = fmaf(sv, kw, ak[ri]);
    }
  }
  #pragma unroll
  for (int ri = 0; ri < 4; ++ri) {
    int row = row0 + wv * 4 + ri;
    q_b[row * HID_ + lane] = f2bf(aq[ri] * 0.08838834764831845f);  // fold 1/sqrt(128)
    k_b[row * HID_ + lane] = f2bf(ak[ri]);
  }
}

// ---------------- Kernel B: MFMA attention + c_feat ----------------
// 256 blocks (lb, half) x 512 threads (8 waves); wave = one 16-row l-tile.
#define PK 72    // row stride (ushort) for k/q/sn/so tiles
#define PT 264   // row stride for st (s transposed)
#define PW 136   // row stride for w2
__global__ __launch_bounds__(512, 1) void kB_attn(
    const unsigned short* __restrict__ qb, const unsigned short* __restrict__ kb,
    const unsigned short* __restrict__ sb, const int* __restrict__ Gmat,
    const float* __restrict__ W2, const float* __restrict__ b2,
    float* __restrict__ cfeat) {
  __shared__ __attribute__((aligned(16))) unsigned short k_lds[256 * PK];
  __shared__ __attribute__((aligned(16))) unsigned short q_lds[128 * PK];
  __shared__ __attribute__((aligned(16))) unsigned short sn_lds[128 * PK];
  __shared__ __attribute__((aligned(16))) unsigned short st_lds[64 * PT];
  __shared__ __attribute__((aligned(16))) unsigned short w2_lds[64 * PW];
  __shared__ __attribute__((aligned(16))) unsigned short so_lds[128 * PK];
  __shared__ unsigned g_lds[128 * 9];
  int tid = threadIdx.x;
  int blk = blockIdx.x;
  int lb = blk >> 1;
  int l0 = (blk & 1) << 7;   // m-range base (att row range)
  const unsigned short* kg = kb + lb * 256 * 64;
  const unsigned short* qg = qb + (lb * 256 + l0) * 64;
  const unsigned short* sg0 = sb + lb * 256 * 64;
  const unsigned short* sg1 = sb + (lb * 256 + l0) * 64;
  // stage k (256x64), q/sn (128x64) as uint4 chunks
  for (int i = tid; i < 2048; i += 512) {
    int s = i >> 3, e8 = (i & 7) * 8;
    *(uint4*)&k_lds[s * PK + e8] = *(const uint4*)(kg + s * 64 + e8);
  }
  for (int i = tid; i < 1024; i += 512) {
    int r = i >> 3, e8 = (i & 7) * 8;
    *(uint4*)&q_lds[r * PK + e8] = *(const uint4*)(qg + r * 64 + e8);
    *(uint4*)&sn_lds[r * PK + e8] = *(const uint4*)(sg1 + r * 64 + e8);
  }
  for (int i = tid; i < 16384; i += 512) {  // s transpose: st[e][s]
    int s = i >> 6, e = i & 63;
    st_lds[e * PT + s] = sg0[s * 64 + e];
  }
  for (int i = tid; i < 8192; i += 512) {   // W2 [64][128] f32 -> bf16
    int t = i >> 7, j = i & 127;
    w2_lds[t * PW + j] = f2bf(W2[i]);
  }
  {
    int w = tid >> 6, ln = tid & 63;
    for (int li = w; li < 128; li += 8) {
      #pragma unroll
      for (int c = 0; c < 4; ++c) {
        int g = Gmat[(l0 + li) * 256 + c * 64 + ln];
        unsigned long long mask = __ballot(g > 0);
        if (ln == 0) {
          g_lds[li * 9 + c * 2] = (unsigned)mask;
          g_lds[li * 9 + c * 2 + 1] = (unsigned)(mask >> 32);
        }
      }
    }
  }
  __syncthreads();

  int lane = tid & 63, w = tid >> 6;
  int c16 = lane & 15, q4 = lane >> 4;
  int lrow0 = w * 16;
  const bf16x8 z8 = {0, 0, 0, 0, 0, 0, 0, 0};
  // B-frags of q (att): B[k=e][n=l]; lanes q4>=2 are the zero K-padding
  bf16x8 bq[4];
  #pragma unroll
  for (int h = 0; h < 4; ++h) {
    bq[h] = (q4 < 2) ? *(const bf16x8*)&q_lds[(lrow0 + c16) * PK + h * 16 + q4 * 8] : z8;
  }
  f32x4 accO[4];
  float sumh[4];
  #pragma unroll
  for (int h = 0; h < 4; ++h) { accO[h] = (f32x4){0.f, 0.f, 0.f, 0.f}; sumh[h] = 0.f; }

  for (int sp = 0; sp < 8; ++sp) {          // 32-wide s chunks
    unsigned gw = g_lds[(lrow0 + c16) * 9 + sp];
    #pragma unroll
    for (int h = 0; h < 4; ++h) {
      unsigned pk0A, pk1A, pk0B, pk1B;
      #pragma unroll
      for (int tp = 0; tp < 2; ++tp) {
        int t = sp * 2 + tp;                // 16-wide s tile
        bf16x8 ka = (q4 < 2) ? *(const bf16x8*)&k_lds[(t * 16 + c16) * PK + h * 16 + q4 * 8] : z8;
        f32x4 d = __builtin_amdgcn_mfma_f32_16x16x32_bf16(ka, bq[h], (f32x4){0.f, 0.f, 0.f, 0.f}, 0, 0, 0);
        int bitbase = tp * 16 + q4 * 4;
        float p0 = ((gw >> (bitbase + 0)) & 1u) ? __expf(d[0]) : 0.f;
        float p1 = ((gw >> (bitbase + 1)) & 1u) ? __expf(d[1]) : 0.f;
        float p2 = ((gw >> (bitbase + 2)) & 1u) ? __expf(d[2]) : 0.f;
        float p3 = ((gw >> (bitbase + 3)) & 1u) ? __expf(d[3]) : 0.f;
        sumh[h] += (p0 + p1) + (p2 + p3);
        unsigned lo = (unsigned)f2bf(p0) | ((unsigned)f2bf(p1) << 16);
        unsigned hi = (unsigned)f2bf(p2) | ((unsigned)f2bf(p3) << 16);
        if (tp == 0) { pk0A = lo; pk1A = hi; } else { pk0B = lo; pk1B = hi; }
      }
      // assemble PV A-frag: lane holds P[l=c16][s = sp*32 + q4*8 + j], j=0..7
      int srcA = ((q4 & 1) * 2) * 16 + c16, srcB = srcA + 16;
      unsigned g0A = (unsigned)__shfl((int)pk0A, srcA);
      unsigned g1A = (unsigned)__shfl((int)pk1A, srcA);
      unsigned g2A = (unsigned)__shfl((int)pk0A, srcB);
      unsigned g3A = (unsigned)__shfl((int)pk1A, srcB);
      unsigned g0B = (unsigned)__shfl((int)pk0B, srcA);
      unsigned g1B = (unsigned)__shfl((int)pk1B, srcA);
      unsigned g2B = (unsigned)__shfl((int)pk0B, srcB);
      unsigned g3B = (unsigned)__shfl((int)pk1B, srcB);
      bool useB = (q4 >= 2);
      uint4 av;
      av.x = useB ? g0B : g0A;
      av.y = useB ? g1B : g1A;
      av.z = useB ? g2B : g2A;
      av.w = useB ? g3B : g3A;
      bf16x8 af = __builtin_bit_cast(bf16x8, av);
      bf16x8 bs = *(const bf16x8*)&st_lds[(h * 16 + c16) * PT + sp * 32 + q4 * 8];
      accO[h] = __builtin_amdgcn_mfma_f32_16x16x32_bf16(af, bs, accO[h], 0, 0, 0);
    }
  }
  // normalize + write s_out (bf16) to so_lds in natural [l][e] layout
  #pragma unroll
  for (int h = 0; h < 4; ++h) {
    float s = sumh[h];
    s += __shfl_xor(s, 16);
    s += __shfl_xor(s, 32);
    #pragma unroll
    for (int r = 0; r < 4; ++r) {
      float sv = __shfl(s, q4 * 4 + r);
      float o = accO[h][r] / sv;
      so_lds[(lrow0 + q4 * 4 + r) * PK + h * 16 + c16] = f2bf(o);
    }
  }
  __syncthreads();
  // c_feat = [s, s_out] @ W2.T + b2  (per wave: 16 l-rows x 64 t)
  #pragma unroll
  for (int tt = 0; tt < 4; ++tt) {
    f32x4 cf = {0.f, 0.f, 0.f, 0.f};
    #pragma unroll
    for (int kt = 0; kt < 4; ++kt) {
      bf16x8 af = (kt < 2)
        ? *(const bf16x8*)&sn_lds[(lrow0 + c16) * PK + kt * 32 + q4 * 8]
        : *(const bf16x8*)&so_lds[(lrow0 + c16) * PK + (kt - 2) * 32 + q4 * 8];
      bf16x8 bw = *(const bf16x8*)&w2_lds[(tt * 16 + c16) * PW + kt * 32 + q4 * 8];
      cf = __builtin_amdgcn_mfma_f32_16x16x32_bf16(af, bw, cf, 0, 0, 0);
    }
    float bias = b2[tt * 16 + c16];
    #pragma unroll
    for (int r = 0; r < 4; ++r) {
      int lrow = l0 + lrow0 + q4 * 4 + r;
      cfeat[(lb * 256 + lrow) * 64 + tt * 16 + c16] = cf[r] + bias;
    }
  }
}

// ---------------- K4: LSTM (actor blocks 0..511, critic 512..1023; 4 seqs/block) ----------------
__global__ __launch_bounds__(256) void k4_lstm(const float* __restrict__ a_lin,
    const float* __restrict__ c_feat,
    const float* __restrict__ Wih_a, const float* __restrict__ Whh_a,
    const float* __restrict__ bih_a, const float* __restrict__ bhh_a,
    const float* __restrict__ Wih_c, const float* __restrict__ Whh_c,
    const float* __restrict__ bih_c, const float* __restrict__ bhh_c,
    float* __restrict__ ah, float* __restrict__ ch) {
  int blk = blockIdx.x;
  int which = blk >> 9;
  int g = blk & 511;
  const float* xin = which ? c_feat : a_lin;
  const float* Wih = which ? Wih_c : Wih_a;
  const float* Whh = which ? Whh_c : Whh_a;
  const float* bih = which ? bih_c : bih_a;
  const float* bhh = which ? bhh_c : bhh_a;
  float* hout = which ? ch : ah;
  int t = threadIdx.x;
  int r = t;
  float wih[HID_], whh[HID_];
  #pragma unroll
  for (int j = 0; j < HID_; ++j) {
    wih[j] = Wih[r * HID_ + j];
    whh[j] = Whh[r * HID_ + j];
  }
  float bsum = bih[r] + bhh[r];
  __shared__ __align__(16) float xt[4][HID_];
  __shared__ __align__(16) float hs[4][HID_];
  __shared__ float gates[4][256];
  int sq = t >> 6, kk = t & 63;
  int n = g * 4 + sq;
  int b = n >> 8, m = n & 255;
  hs[sq][kk] = 0.f;
  float cc = 0.f;
  float hlast = 0.f;
  const float* xbase = xin + (b * M_ + m) * HID_ + kk;
  __syncthreads();
  for (int l = 0; l < L_; ++l) {
    xt[sq][kk] = xbase[l * (B_ * M_ * HID_)];
    __syncthreads();
    float acc[4] = {bsum, bsum, bsum, bsum};
    #pragma unroll
    for (int jc = 0; jc < 16; ++jc) {
      float w0 = wih[jc * 4 + 0], w1 = wih[jc * 4 + 1];
      float w2v = wih[jc * 4 + 2], w3v = wih[jc * 4 + 3];
      float u0 = whh[jc * 4 + 0], u1 = whh[jc * 4 + 1];
      float u2v = whh[jc * 4 + 2], u3v = whh[jc * 4 + 3];
      #pragma unroll
      for (int sI = 0; sI < 4; ++sI) {
        float4 xv = ((const float4*)xt[sI])[jc];
        float4 hv = ((const float4*)hs[sI])[jc];
        acc[sI] = fmaf(w0, xv.x, acc[sI]);
        acc[sI] = fmaf(w1, xv.y, acc[sI]);
        acc[sI] = fmaf(w2v, xv.z, acc[sI]);
        acc[sI] = fmaf(w3v, xv.w, acc[sI]);
        acc[sI] = fmaf(u0, hv.x, acc[sI]);
        acc[sI] = fmaf(u1, hv.y, acc[sI]);
        acc[sI] = fmaf(u2v, hv.z, acc[sI]);
        acc[sI] = fmaf(u3v, hv.w, acc[sI]);
      }
    }
    gates[0][r] = acc[0]; gates[1][r] = acc[1];
    gates[2][r] = acc[2]; gates[3][r] = acc[3];
    __syncthreads();
    float gi = gates[sq][kk];
    float gf = gates[sq][kk + 64];
    float gg = gates[sq][kk + 128];
    float go = gates[sq][kk + 192];
    float si = 1.f / (1.f + expf(-gi));
    float sf = 1.f / (1.f + expf(-gf));
    float so = 1.f / (1.f + expf(-go));
    cc = sf * cc + si * tanhf(gg);
    float hv = so * tanhf(cc);
    hs[sq][kk] = hv;
    hlast = hv;
  }
  hout[n * HID_ + kk] = hlast;
}

// ---------------- K5: heads + outputs ----------------
__global__ __launch_bounds__(64) void k5_heads(const float* __restrict__ ah,
    const float* __restrict__ ch, const int* __restrict__ action,
    const float* __restrict__ Wma1, const float* __restrict__ bma1,
    const float* __restrict__ Wma2, const float* __restrict__ bma2,
    const float* __restrict__ Wmc1, const float* __restrict__ bmc1,
    const float* __restrict__ Wmc2, const float* __restrict__ bmc2,
    float* __restrict__ out) {
  int n = blockIdx.x;
  int t = threadIdx.x;
  __shared__ float ha[HID_], hc[HID_], hA[HID_], logit[15], grp[6];
  ha[t] = ah[n * HID_ + t];
  hc[t] = ch[n * HID_ + t];
  __syncthreads();
  float aA = bma1[t], aC = bmc1[t];
  #pragma unroll
  for (int j = 0; j < HID_; ++j) {
    aA = fmaf(ha[j], Wma1[t * HID_ + j], aA);
    aC = fmaf(hc[j], Wmc1[t * HID_ + j], aC);
  }
  float hCt = tanhf(aC);
  hA[t] = tanhf(aA);
  __syncthreads();
  float pv = hCt * Wmc2[t];
  #pragma unroll
  for (int off = 32; off > 0; off >>= 1) pv += __shfl_xor(pv, off);
  if (t < 15) {
    float acc = bma2[t];
    #pragma unroll
    for (int j = 0; j < HID_; ++j) acc = fmaf(hA[j], Wma2[t * HID_ + j], acc);
    logit[t] = acc;
  }
  __syncthreads();
  if (t < 3) {
    float l0 = logit[t * 5 + 0], l1 = logit[t * 5 + 1], l2 = logit[t * 5 + 2];
    float l3 = logit[t * 5 + 3], l4 = logit[t * 5 + 4];
    float mx = fmaxf(fmaxf(fmaxf(l0, l1), fmaxf(l2, l3)), l4);
    float sm = expf(l0 - mx) + expf(l1 - mx) + expf(l2 - mx) + expf(l3 - mx) + expf(l4 - mx);
    float lse = logf(sm) + mx;
    int a = action[n * 3 + t];
    float lp0 = l0 - lse, lp1 = l1 - lse, lp2 = l2 - lse, lp3 = l3 - lse, lp4 = l4 - lse;
    float lpsel = logit[t * 5 + a] - lse;
    float ent = -(expf(lp0) * lp0 + expf(lp1) * lp1 + expf(lp2) * lp2 +
                  expf(lp3) * lp3 + expf(lp4) * lp4);
    grp[t] = lpsel;
    grp[3 + t] = ent;
    out[n * 3 + t] = (float)a;
  }
  __syncthreads();
  if (t == 0) {
    out[6144 + n] = grp[0] + grp[1] + grp[2];
    out[8192 + n] = grp[3] + grp[4] + grp[5];
    out[10240 + n] = pv + bmc2[0];
  }
}

extern "C" void kernel_launch(void* const* d_in, const int* in_sizes, int n_in,
                              void* d_out, int out_size, void* d_ws, size_t ws_size,
                              hipStream_t stream) {
  const float* x_actor = (const float*)d_in[0];
  const int* action = (const int*)d_in[2];
  const int* Gmat  = (const int*)d_in[3];
  const float* Wa = (const float*)d_in[4];  const float* ba = (const float*)d_in[5];
  const float* Wg = (const float*)d_in[6];  const float* bg = (const float*)d_in[7];
  const float* Qw = (const float*)d_in[8];  const float* Kw = (const float*)d_in[9];
  const float* W2 = (const float*)d_in[10]; const float* b2 = (const float*)d_in[11];
  const float* Wih_a = (const float*)d_in[12]; const float* Whh_a = (const float*)d_in[13];
  const float* bih_a = (const float*)d_in[14]; const float* bhh_a = (const float*)d_in[15];
  const float* Wih_c = (const float*)d_in[16]; const float* Whh_c = (const float*)d_in[17];
  const float* bih_c = (const float*)d_in[18]; const float* bhh_c = (const float*)d_in[19];
  const float* Wma1 = (const float*)d_in[20]; const float* bma1 = (const float*)d_in[21];
  const float* Wma2 = (const float*)d_in[22]; const float* bma2 = (const float*)d_in[23];
  const float* Wmc1 = (const float*)d_in[24]; const float* bmc1 = (const float*)d_in[25];
  const float* Wmc2 = (const float*)d_in[26]; const float* bmc2 = (const float*)d_in[27];

  float* ws = (float*)d_ws;
  float* a_lin = ws;                               // 2,097,152 f32
  float* cfeat = ws + 2097152;                     // 2,097,152 f32
  float* ah    = ws + 4194304;                     // 131,072
  float* ch    = ws + 4325376;                     // 131,072
  unsigned short* s_b = (unsigned short*)(ws + 4456448);  // 2,097,152 ushort
  unsigned short* q_b = (unsigned short*)(ws + 5505024);
  unsigned short* k_b = (unsigned short*)(ws + 6553600);
  float* out = (float*)d_out;

  kA_lin<<<2048, 256, 0, stream>>>(x_actor, Wa, ba, Wg, bg, Qw, Kw,
                                   a_lin, s_b, q_b, k_b);
  kB_attn<<<256, 512, 0, stream>>>(q_b, k_b, s_b, Gmat, W2, b2, cfeat);
  k4_lstm<<<1024, 256, 0, stream>>>(a_lin, cfeat, Wih_a, Whh_a, bih_a, bhh_a,
                                    Wih_c, Whh_c, bih_c, bhh_c, ah, ch);
  k5_heads<<<2048, 64, 0, stream>>>(ah, ch, action, Wma1, bma1, Wma2, bma2,
                                    Wmc1, bmc1, Wmc2, bmc2, out);
}

// Round 3
// 121.312 us; speedup vs baseline: 5.6099x; 1.6742x over previous
//
#include <hip/hip_runtime.h>
#include <math.h>

#define B_ 8
#define L_ 16
#define M_ 256
#define H_ 53
#define HID_ 64
#define LB_ 128  // L_*B_

typedef __attribute__((ext_vector_type(8))) short bf16x8;
typedef __attribute__((ext_vector_type(4))) float f32x4;

__device__ inline unsigned short f2bf(float f) {
  unsigned u = __builtin_bit_cast(unsigned, f);
  unsigned r = (u + 0x7FFFu + ((u >> 16) & 1u)) >> 16;
  return (unsigned short)r;
}
__device__ inline float bf2f(unsigned short u) {
  unsigned v = ((unsigned)u) << 16;
  return __builtin_bit_cast(float, v);
}

// ---------------- Kernel A: fused  a_lin/s (x@W.T) + q/k (s@Qw, s@Kw) ----------------
__global__ __launch_bounds__(256) void kA_lin(const float* __restrict__ x,
    const float* __restrict__ Wa, const float* __restrict__ ba,
    const float* __restrict__ Wg, const float* __restrict__ bg,
    const float* __restrict__ Qw, const float* __restrict__ Kw,
    unsigned short* __restrict__ a_lin_bf, unsigned short* __restrict__ s_b,
    unsigned short* __restrict__ q_b, unsigned short* __restrict__ k_b) {
  __shared__ float wa_lds[HID_ * H_];
  __shared__ float wg_lds[HID_ * H_];
  __shared__ float x_lds[16][H_];
  __shared__ float s_sh[16][HID_];
  int tid = threadIdx.x;
  int row0 = blockIdx.x * 16;
  for (int i = tid; i < HID_ * H_; i += 256) { wa_lds[i] = Wa[i]; wg_lds[i] = Wg[i]; }
  for (int i = tid; i < 16 * H_; i += 256) {
    int r = i / H_, j = i - r * H_;
    int row = row0 + r;
    int lb = row >> 8, m = row & 255;
    int l = lb >> 3, b = lb & 7;
    x_lds[r][j] = x[((b * L_ + l) * M_ + m) * H_ + j];
  }
  __syncthreads();
  int lane = tid & 63, wv = tid >> 6;
  float aA[4], aS[4];
  float bav = ba[lane], bgv = bg[lane];
  #pragma unroll
  for (int ri = 0; ri < 4; ++ri) { aA[ri] = bav; aS[ri] = bgv; }
  for (int j = 0; j < H_; ++j) {
    float wa = wa_lds[lane * H_ + j];
    float wg = wg_lds[lane * H_ + j];
    #pragma unroll
    for (int ri = 0; ri < 4; ++ri) {
      float xv = x_lds[wv * 4 + ri][j];
      aA[ri] = fmaf(xv, wa, aA[ri]);
      aS[ri] = fmaf(xv, wg, aS[ri]);
    }
  }
  #pragma unroll
  for (int ri = 0; ri < 4; ++ri) {
    int row = row0 + wv * 4 + ri;
    a_lin_bf[row * HID_ + lane] = f2bf(aA[ri]);
    s_sh[wv * 4 + ri][lane] = aS[ri];
    s_b[row * HID_ + lane] = f2bf(aS[ri]);
  }
  __syncthreads();
  float aq[4] = {0.f, 0.f, 0.f, 0.f}, ak[4] = {0.f, 0.f, 0.f, 0.f};
  for (int j = 0; j < HID_; ++j) {
    float qw = Qw[j * HID_ + lane];
    float kw = Kw[j * HID_ + lane];
    #pragma unroll
    for (int ri = 0; ri < 4; ++ri) {
      float sv = s_sh[wv * 4 + ri][j];
      aq[ri] = fmaf(sv, qw, aq[ri]);
      ak[ri] = fmaf(sv, kw, ak[ri]);
    }
  }
  #pragma unroll
  for (int ri = 0; ri < 4; ++ri) {
    int row = row0 + wv * 4 + ri;
    q_b[row * HID_ + lane] = f2bf(aq[ri] * 0.08838834764831845f);  // fold 1/sqrt(128)
    k_b[row * HID_ + lane] = f2bf(ak[ri]);
  }
}

// ---------------- Kernel B: MFMA attention + c_feat ----------------
#define PK 72    // row stride (ushort) for k/q/sn/so tiles
#define PT 264   // row stride for st (s transposed)
#define PW 136   // row stride for w2
__global__ __launch_bounds__(512, 1) void kB_attn(
    const unsigned short* __restrict__ qb, const unsigned short* __restrict__ kb,
    const unsigned short* __restrict__ sb, const int* __restrict__ Gmat,
    const float* __restrict__ W2, const float* __restrict__ b2,
    unsigned short* __restrict__ cfeat_bf) {
  __shared__ __attribute__((aligned(16))) unsigned short k_lds[256 * PK];
  __shared__ __attribute__((aligned(16))) unsigned short q_lds[128 * PK];
  __shared__ __attribute__((aligned(16))) unsigned short sn_lds[128 * PK];
  __shared__ __attribute__((aligned(16))) unsigned short st_lds[64 * PT];
  __shared__ __attribute__((aligned(16))) unsigned short w2_lds[64 * PW];
  __shared__ __attribute__((aligned(16))) unsigned short so_lds[128 * PK];
  __shared__ unsigned g_lds[128 * 9];
  int tid = threadIdx.x;
  int blk = blockIdx.x;
  int lb = blk >> 1;
  int l0 = (blk & 1) << 7;
  const unsigned short* kg = kb + lb * 256 * 64;
  const unsigned short* qg = qb + (lb * 256 + l0) * 64;
  const unsigned short* sg0 = sb + lb * 256 * 64;
  const unsigned short* sg1 = sb + (lb * 256 + l0) * 64;
  for (int i = tid; i < 2048; i += 512) {
    int s = i >> 3, e8 = (i & 7) * 8;
    *(uint4*)&k_lds[s * PK + e8] = *(const uint4*)(kg + s * 64 + e8);
  }
  for (int i = tid; i < 1024; i += 512) {
    int r = i >> 3, e8 = (i & 7) * 8;
    *(uint4*)&q_lds[r * PK + e8] = *(const uint4*)(qg + r * 64 + e8);
    *(uint4*)&sn_lds[r * PK + e8] = *(const uint4*)(sg1 + r * 64 + e8);
  }
  for (int i = tid; i < 16384; i += 512) {
    int s = i >> 6, e = i & 63;
    st_lds[e * PT + s] = sg0[s * 64 + e];
  }
  for (int i = tid; i < 8192; i += 512) {
    int t = i >> 7, j = i & 127;
    w2_lds[t * PW + j] = f2bf(W2[i]);
  }
  {
    int w = tid >> 6, ln = tid & 63;
    for (int li = w; li < 128; li += 8) {
      #pragma unroll
      for (int c = 0; c < 4; ++c) {
        int g = Gmat[(l0 + li) * 256 + c * 64 + ln];
        unsigned long long mask = __ballot(g > 0);
        if (ln == 0) {
          g_lds[li * 9 + c * 2] = (unsigned)mask;
          g_lds[li * 9 + c * 2 + 1] = (unsigned)(mask >> 32);
        }
      }
    }
  }
  __syncthreads();

  int lane = tid & 63, w = tid >> 6;
  int c16 = lane & 15, q4 = lane >> 4;
  int lrow0 = w * 16;
  const bf16x8 z8 = {0, 0, 0, 0, 0, 0, 0, 0};
  bf16x8 bq[4];
  #pragma unroll
  for (int h = 0; h < 4; ++h) {
    bq[h] = (q4 < 2) ? *(const bf16x8*)&q_lds[(lrow0 + c16) * PK + h * 16 + q4 * 8] : z8;
  }
  f32x4 accO[4];
  float sumh[4];
  #pragma unroll
  for (int h = 0; h < 4; ++h) { accO[h] = (f32x4){0.f, 0.f, 0.f, 0.f}; sumh[h] = 0.f; }

  for (int sp = 0; sp < 8; ++sp) {
    unsigned gw = g_lds[(lrow0 + c16) * 9 + sp];
    #pragma unroll
    for (int h = 0; h < 4; ++h) {
      unsigned pk0A, pk1A, pk0B, pk1B;
      #pragma unroll
      for (int tp = 0; tp < 2; ++tp) {
        int t = sp * 2 + tp;
        bf16x8 ka = (q4 < 2) ? *(const bf16x8*)&k_lds[(t * 16 + c16) * PK + h * 16 + q4 * 8] : z8;
        f32x4 d = __builtin_amdgcn_mfma_f32_16x16x32_bf16(ka, bq[h], (f32x4){0.f, 0.f, 0.f, 0.f}, 0, 0, 0);
        int bitbase = tp * 16 + q4 * 4;
        float p0 = ((gw >> (bitbase + 0)) & 1u) ? __expf(d[0]) : 0.f;
        float p1 = ((gw >> (bitbase + 1)) & 1u) ? __expf(d[1]) : 0.f;
        float p2 = ((gw >> (bitbase + 2)) & 1u) ? __expf(d[2]) : 0.f;
        float p3 = ((gw >> (bitbase + 3)) & 1u) ? __expf(d[3]) : 0.f;
        sumh[h] += (p0 + p1) + (p2 + p3);
        unsigned lo = (unsigned)f2bf(p0) | ((unsigned)f2bf(p1) << 16);
        unsigned hi = (unsigned)f2bf(p2) | ((unsigned)f2bf(p3) << 16);
        if (tp == 0) { pk0A = lo; pk1A = hi; } else { pk0B = lo; pk1B = hi; }
      }
      int srcA = ((q4 & 1) * 2) * 16 + c16, srcB = srcA + 16;
      unsigned g0A = (unsigned)__shfl((int)pk0A, srcA);
      unsigned g1A = (unsigned)__shfl((int)pk1A, srcA);
      unsigned g2A = (unsigned)__shfl((int)pk0A, srcB);
      unsigned g3A = (unsigned)__shfl((int)pk1A, srcB);
      unsigned g0B = (unsigned)__shfl((int)pk0B, srcA);
      unsigned g1B = (unsigned)__shfl((int)pk1B, srcA);
      unsigned g2B = (unsigned)__shfl((int)pk0B, srcB);
      unsigned g3B = (unsigned)__shfl((int)pk1B, srcB);
      bool useB = (q4 >= 2);
      uint4 av;
      av.x = useB ? g0B : g0A;
      av.y = useB ? g1B : g1A;
      av.z = useB ? g2B : g2A;
      av.w = useB ? g3B : g3A;
      bf16x8 af = __builtin_bit_cast(bf16x8, av);
      bf16x8 bs = *(const bf16x8*)&st_lds[(h * 16 + c16) * PT + sp * 32 + q4 * 8];
      accO[h] = __builtin_amdgcn_mfma_f32_16x16x32_bf16(af, bs, accO[h], 0, 0, 0);
    }
  }
  #pragma unroll
  for (int h = 0; h < 4; ++h) {
    float s = sumh[h];
    s += __shfl_xor(s, 16);
    s += __shfl_xor(s, 32);
    #pragma unroll
    for (int r = 0; r < 4; ++r) {
      float sv = __shfl(s, q4 * 4 + r);
      float o = accO[h][r] / sv;
      so_lds[(lrow0 + q4 * 4 + r) * PK + h * 16 + c16] = f2bf(o);
    }
  }
  __syncthreads();
  #pragma unroll
  for (int tt = 0; tt < 4; ++tt) {
    f32x4 cf = {0.f, 0.f, 0.f, 0.f};
    #pragma unroll
    for (int kt = 0; kt < 4; ++kt) {
      bf16x8 af = (kt < 2)
        ? *(const bf16x8*)&sn_lds[(lrow0 + c16) * PK + kt * 32 + q4 * 8]
        : *(const bf16x8*)&so_lds[(lrow0 + c16) * PK + (kt - 2) * 32 + q4 * 8];
      bf16x8 bw = *(const bf16x8*)&w2_lds[(tt * 16 + c16) * PW + kt * 32 + q4 * 8];
      cf = __builtin_amdgcn_mfma_f32_16x16x32_bf16(af, bw, cf, 0, 0, 0);
    }
    float bias = b2[tt * 16 + c16];
    #pragma unroll
    for (int r = 0; r < 4; ++r) {
      int lrow = l0 + lrow0 + q4 * 4 + r;
      cfeat_bf[(lb * 256 + lrow) * 64 + tt * 16 + c16] = f2bf(cf[r] + bias);
    }
  }
}

// ---------------- K4a: gx = in @ Wih.T  (all timesteps, both LSTMs) ----------------
// 512 blocks: which = blk>>8, t = blk&255 -> rows t*128..t*128+127 of [32768,64] bf16.
// Output gx[which][seq][l][gate] bf16 (seq = b*256+m, row = (l*8+b)*256+m).
__global__ __launch_bounds__(512, 1) void k4a_gx(
    const unsigned short* __restrict__ a_lin_bf,
    const unsigned short* __restrict__ cfeat_bf,
    const float* __restrict__ Wih_a, const float* __restrict__ Wih_c,
    unsigned short* __restrict__ gx) {
  int blk = blockIdx.x;
  int which = blk >> 8, t = blk & 255;
  const unsigned short* in = which ? cfeat_bf : a_lin_bf;
  const float* Wih = which ? Wih_c : Wih_a;
  unsigned short* gxo = gx + which * 8388608;
  __shared__ __attribute__((aligned(16))) unsigned short in_lds[128 * 72];
  __shared__ __attribute__((aligned(16))) unsigned short wih_lds[256 * 72];
  int tid = threadIdx.x;
  int r0 = t * 128;
  #pragma unroll
  for (int i = tid; i < 1024; i += 512) {
    int row = i >> 3, ch = i & 7;
    *(uint4*)&in_lds[row * 72 + ch * 8] = *(const uint4*)(in + (r0 + row) * 64 + ch * 8);
  }
  for (int i = tid; i < 16384; i += 512) {
    wih_lds[(i >> 6) * 72 + (i & 63)] = f2bf(Wih[i]);
  }
  __syncthreads();
  int lane = tid & 63, w = tid >> 6;
  int c16 = lane & 15, q4 = lane >> 4;
  int lb = t >> 1, l = lb >> 3, b = lb & 7, m0 = (t & 1) * 128;
  bf16x8 a0 = *(const bf16x8*)&in_lds[(w * 16 + c16) * 72 + q4 * 8];
  bf16x8 a1 = *(const bf16x8*)&in_lds[(w * 16 + c16) * 72 + 32 + q4 * 8];
  int seqb = b * 256 + m0 + w * 16 + q4 * 4;
  #pragma unroll
  for (int nt = 0; nt < 16; ++nt) {
    bf16x8 b0 = *(const bf16x8*)&wih_lds[(nt * 16 + c16) * 72 + q4 * 8];
    bf16x8 b1 = *(const bf16x8*)&wih_lds[(nt * 16 + c16) * 72 + 32 + q4 * 8];
    f32x4 acc = {0.f, 0.f, 0.f, 0.f};
    acc = __builtin_amdgcn_mfma_f32_16x16x32_bf16(a0, b0, acc, 0, 0, 0);
    acc = __builtin_amdgcn_mfma_f32_16x16x32_bf16(a1, b1, acc, 0, 0, 0);
    #pragma unroll
    for (int rr = 0; rr < 4; ++rr) {
      gxo[((seqb + rr) * 16 + l) * 256 + nt * 16 + c16] = f2bf(acc[rr]);
    }
  }
}

// ---------------- K4b: LSTM recurrence via MFMA ----------------
// 256 blocks: which = blk>>7, g = blk&127 -> seqs g*16..g*16+15. 256 threads, 4 waves.
// Wave w: gates n0=w*64..n0+63. Whh B-frags in registers for all 16 steps.
__global__ __launch_bounds__(256, 1) void k4b_rec(
    const unsigned short* __restrict__ gx,
    const float* __restrict__ Whh_a, const float* __restrict__ Whh_c,
    const float* __restrict__ bih_a, const float* __restrict__ bhh_a,
    const float* __restrict__ bih_c, const float* __restrict__ bhh_c,
    float* __restrict__ ah, float* __restrict__ ch) {
  int blk = blockIdx.x;
  int which = blk >> 7, g = blk & 127;
  int seq0 = g * 16;
  const unsigned short* gxp = gx + which * 8388608 + seq0 * (16 * 256);
  const float* Whh = which ? Whh_c : Whh_a;
  const float* bih = which ? bih_c : bih_a;
  const float* bhh = which ? bhh_c : bhh_a;
  float* hout = which ? ch : ah;
  __shared__ __attribute__((aligned(16))) unsigned short h_lds[16 * 72];
  __shared__ __attribute__((aligned(16))) float gates_lds[16 * 264];
  int tid = threadIdx.x;
  int lane = tid & 63, w = tid >> 6;
  int c16 = lane & 15, q4 = lane >> 4;
  int n0 = w * 64;
  // Whh B-frags in registers (step-invariant)
  bf16x8 bw[4][2];
  #pragma unroll
  for (int nt = 0; nt < 4; ++nt) {
    #pragma unroll
    for (int kf = 0; kf < 2; ++kf) {
      const float* wp = Whh + (n0 + nt * 16 + c16) * 64 + kf * 32 + q4 * 8;
      bf16x8 bb;
      #pragma unroll
      for (int j = 0; j < 8; ++j) bb[j] = (short)f2bf(wp[j]);
      bw[nt][kf] = bb;
    }
  }
  // update-thread identity: (seq, 4 hid elems)
  int useq = tid >> 4, hidb = (tid & 15) * 4;
  float4 bsv[4];
  #pragma unroll
  for (int gi = 0; gi < 4; ++gi) {
    float4 u = *(const float4*)&bih[gi * 64 + hidb];
    float4 v = *(const float4*)&bhh[gi * 64 + hidb];
    bsv[gi] = make_float4(u.x + v.x, u.y + v.y, u.z + v.z, u.w + v.w);
  }
  // init h = 0, c = 0
  *(uint2*)&h_lds[useq * 72 + hidb] = make_uint2(0u, 0u);
  float cr[4] = {0.f, 0.f, 0.f, 0.f};
  float hv[4] = {0.f, 0.f, 0.f, 0.f};
  __syncthreads();

  // gx prefetch double buffer (16 values per lane per step)
  unsigned short gxu[2][16];
  #pragma unroll
  for (int i = 0; i < 16; ++i) {
    int nt = i >> 2, rr = i & 3;
    gxu[0][i] = gxp[((q4 * 4 + rr) * 16 + 0) * 256 + n0 + nt * 16 + c16];
  }
  #pragma unroll
  for (int l = 0; l < L_; ++l) {
    const int pb = l & 1;
    if (l < L_ - 1) {
      #pragma unroll
      for (int i = 0; i < 16; ++i) {
        int nt = i >> 2, rr = i & 3;
        gxu[pb ^ 1][i] = gxp[((q4 * 4 + rr) * 16 + (l + 1)) * 256 + n0 + nt * 16 + c16];
      }
    }
    bf16x8 a0 = *(const bf16x8*)&h_lds[c16 * 72 + q4 * 8];
    bf16x8 a1 = *(const bf16x8*)&h_lds[c16 * 72 + 32 + q4 * 8];
    #pragma unroll
    for (int nt = 0; nt < 4; ++nt) {
      f32x4 acc = {0.f, 0.f, 0.f, 0.f};
      acc = __builtin_amdgcn_mfma_f32_16x16x32_bf16(a0, bw[nt][0], acc, 0, 0, 0);
      acc = __builtin_amdgcn_mfma_f32_16x16x32_bf16(a1, bw[nt][1], acc, 0, 0, 0);
      #pragma unroll
      for (int rr = 0; rr < 4; ++rr) {
        gates_lds[(q4 * 4 + rr) * 264 + n0 + nt * 16 + c16] = acc[rr] + bf2f(gxu[pb][nt * 4 + rr]);
      }
    }
    __syncthreads();
    {
      float4 gi4 = *(const float4*)&gates_lds[useq * 264 + hidb];
      float4 gf4 = *(const float4*)&gates_lds[useq * 264 + 64 + hidb];
      float4 gg4 = *(const float4*)&gates_lds[useq * 264 + 128 + hidb];
      float4 go4 = *(const float4*)&gates_lds[useq * 264 + 192 + hidb];
      float gi[4] = {gi4.x + bsv[0].x, gi4.y + bsv[0].y, gi4.z + bsv[0].z, gi4.w + bsv[0].w};
      float gf[4] = {gf4.x + bsv[1].x, gf4.y + bsv[1].y, gf4.z + bsv[1].z, gf4.w + bsv[1].w};
      float gg[4] = {gg4.x + bsv[2].x, gg4.y + bsv[2].y, gg4.z + bsv[2].z, gg4.w + bsv[2].w};
      float go[4] = {go4.x + bsv[3].x, go4.y + bsv[3].y, go4.z + bsv[3].z, go4.w + bsv[3].w};
      unsigned hp[2];
      unsigned short hb[4];
      #pragma unroll
      for (int e = 0; e < 4; ++e) {
        float si = 1.f / (1.f + __expf(-gi[e]));
        float sf = 1.f / (1.f + __expf(-gf[e]));
        float so = 1.f / (1.f + __expf(-go[e]));
        cr[e] = sf * cr[e] + si * tanhf(gg[e]);
        hv[e] = so * tanhf(cr[e]);
        hb[e] = f2bf(hv[e]);
      }
      hp[0] = (unsigned)hb[0] | ((unsigned)hb[1] << 16);
      hp[1] = (unsigned)hb[2] | ((unsigned)hb[3] << 16);
      *(uint2*)&h_lds[useq * 72 + hidb] = make_uint2(hp[0], hp[1]);
    }
    __syncthreads();
  }
  // write final h (f32)
  float4 ho = make_float4(hv[0], hv[1], hv[2], hv[3]);
  *(float4*)&hout[(seq0 + useq) * 64 + hidb] = ho;
}

// ---------------- K5: heads + outputs ----------------
__global__ __launch_bounds__(64) void k5_heads(const float* __restrict__ ah,
    const float* __restrict__ ch, const int* __restrict__ action,
    const float* __restrict__ Wma1, const float* __restrict__ bma1,
    const float* __restrict__ Wma2, const float* __restrict__ bma2,
    const float* __restrict__ Wmc1, const float* __restrict__ bmc1,
    const float* __restrict__ Wmc2, const float* __restrict__ bmc2,
    float* __restrict__ out) {
  int n = blockIdx.x;
  int t = threadIdx.x;
  __shared__ float ha[HID_], hc[HID_], hA[HID_], logit[15], grp[6];
  ha[t] = ah[n * HID_ + t];
  hc[t] = ch[n * HID_ + t];
  __syncthreads();
  float aA = bma1[t], aC = bmc1[t];
  #pragma unroll
  for (int j = 0; j < HID_; ++j) {
    aA = fmaf(ha[j], Wma1[t * HID_ + j], aA);
    aC = fmaf(hc[j], Wmc1[t * HID_ + j], aC);
  }
  float hCt = tanhf(aC);
  hA[t] = tanhf(aA);
  __syncthreads();
  float pv = hCt * Wmc2[t];
  #pragma unroll
  for (int off = 32; off > 0; off >>= 1) pv += __shfl_xor(pv, off);
  if (t < 15) {
    float acc = bma2[t];
    #pragma unroll
    for (int j = 0; j < HID_; ++j) acc = fmaf(hA[j], Wma2[t * HID_ + j], acc);
    logit[t] = acc;
  }
  __syncthreads();
  if (t < 3) {
    float l0 = logit[t * 5 + 0], l1 = logit[t * 5 + 1], l2 = logit[t * 5 + 2];
    float l3 = logit[t * 5 + 3], l4 = logit[t * 5 + 4];
    float mx = fmaxf(fmaxf(fmaxf(l0, l1), fmaxf(l2, l3)), l4);
    float sm = expf(l0 - mx) + expf(l1 - mx) + expf(l2 - mx) + expf(l3 - mx) + expf(l4 - mx);
    float lse = logf(sm) + mx;
    int a = action[n * 3 + t];
    float lp0 = l0 - lse, lp1 = l1 - lse, lp2 = l2 - lse, lp3 = l3 - lse, lp4 = l4 - lse;
    float lpsel = logit[t * 5 + a] - lse;
    float ent = -(expf(lp0) * lp0 + expf(lp1) * lp1 + expf(lp2) * lp2 +
                  expf(lp3) * lp3 + expf(lp4) * lp4);
    grp[t] = lpsel;
    grp[3 + t] = ent;
    out[n * 3 + t] = (float)a;
  }
  __syncthreads();
  if (t == 0) {
    out[6144 + n] = grp[0] + grp[1] + grp[2];
    out[8192 + n] = grp[3] + grp[4] + grp[5];
    out[10240 + n] = pv + bmc2[0];
  }
}

extern "C" void kernel_launch(void* const* d_in, const int* in_sizes, int n_in,
                              void* d_out, int out_size, void* d_ws, size_t ws_size,
                              hipStream_t stream) {
  const float* x_actor = (const float*)d_in[0];
  const int* action = (const int*)d_in[2];
  const int* Gmat  = (const int*)d_in[3];
  const float* Wa = (const float*)d_in[4];  const float* ba = (const float*)d_in[5];
  const float* Wg = (const float*)d_in[6];  const float* bg = (const float*)d_in[7];
  const float* Qw = (const float*)d_in[8];  const float* Kw = (const float*)d_in[9];
  const float* W2 = (const float*)d_in[10]; const float* b2 = (const float*)d_in[11];
  const float* Wih_a = (const float*)d_in[12]; const float* Whh_a = (const float*)d_in[13];
  const float* bih_a = (const float*)d_in[14]; const float* bhh_a = (const float*)d_in[15];
  const float* Wih_c = (const float*)d_in[16]; const float* Whh_c = (const float*)d_in[17];
  const float* bih_c = (const float*)d_in[18]; const float* bhh_c = (const float*)d_in[19];
  const float* Wma1 = (const float*)d_in[20]; const float* bma1 = (const float*)d_in[21];
  const float* Wma2 = (const float*)d_in[22]; const float* bma2 = (const float*)d_in[23];
  const float* Wmc1 = (const float*)d_in[24]; const float* bmc1 = (const float*)d_in[25];
  const float* Wmc2 = (const float*)d_in[26]; const float* bmc2 = (const float*)d_in[27];

  float* ws = (float*)d_ws;
  unsigned short* a_lin_bf = (unsigned short*)ws;                 // 2,097,152 ushort
  unsigned short* cfeat_bf = (unsigned short*)(ws + 1048576);     // 2,097,152 ushort
  unsigned short* s_b = (unsigned short*)(ws + 2097152);
  unsigned short* q_b = (unsigned short*)(ws + 3145728);
  unsigned short* k_b = (unsigned short*)(ws + 4194304);
  unsigned short* gx  = (unsigned short*)(ws + 5242880);          // 16,777,216 ushort
  float* ah = ws + 13631488;                                      // 131,072 f32
  float* ch = ws + 13762560;                                      // 131,072 f32
  float* out = (float*)d_out;

  kA_lin<<<2048, 256, 0, stream>>>(x_actor, Wa, ba, Wg, bg, Qw, Kw,
                                   a_lin_bf, s_b, q_b, k_b);
  kB_attn<<<256, 512, 0, stream>>>(q_b, k_b, s_b, Gmat, W2, b2, cfeat_bf);
  k4a_gx<<<512, 512, 0, stream>>>(a_lin_bf, cfeat_bf, Wih_a, Wih_c, gx);
  k4b_rec<<<256, 256, 0, stream>>>(gx, Whh_a, Whh_c, bih_a, bhh_a, bih_c, bhh_c, ah, ch);
  k5_heads<<<2048, 64, 0, stream>>>(ah, ch, action, Wma1, bma1, Wma2, bma2,
                                    Wmc1, bmc1, Wmc2, bmc2, out);
}

// Round 4
// 104.950 us; speedup vs baseline: 6.4845x; 1.1559x over previous
//
#include <hip/hip_runtime.h>
#include <math.h>

#define B_ 8
#define L_ 16
#define M_ 256
#define H_ 53
#define HID_ 64
#define LB_ 128  // L_*B_

typedef __attribute__((ext_vector_type(8))) short bf16x8;
typedef __attribute__((ext_vector_type(4))) float f32x4;

__device__ inline unsigned short f2bf(float f) {
  unsigned u = __builtin_bit_cast(unsigned, f);
  unsigned r = (u + 0x7FFFu + ((u >> 16) & 1u)) >> 16;
  return (unsigned short)r;
}
__device__ inline float bf2f(unsigned short u) {
  unsigned v = ((unsigned)u) << 16;
  return __builtin_bit_cast(float, v);
}

// ---------------- Kernel A: fused a_lin/s + q/k + sT + (gmask, Wfold duties) ----------------
// 2048 blocks x 256 threads; block handles 16 rows (row = lb*256+m), wave handles 4.
__global__ __launch_bounds__(256) void kA_lin(const float* __restrict__ x,
    const float* __restrict__ Wa, const float* __restrict__ ba,
    const float* __restrict__ Wg, const float* __restrict__ bg,
    const float* __restrict__ Qw, const float* __restrict__ Kw,
    const int* __restrict__ Gmat, const float* __restrict__ Wih_c,
    const float* __restrict__ W2, const float* __restrict__ b2,
    unsigned short* __restrict__ a_lin_bf, unsigned short* __restrict__ s_b,
    unsigned short* __restrict__ q_b, unsigned short* __restrict__ k_b,
    unsigned short* __restrict__ sT_b, unsigned short* __restrict__ Wfold_b,
    float* __restrict__ bias_fold, unsigned* __restrict__ gmask) {
  __shared__ float wa_lds[HID_ * H_];
  __shared__ float wg_lds[HID_ * H_];
  __shared__ float x_lds[16][H_];
  __shared__ float s_sh[16][HID_];
  int tid = threadIdx.x;
  int row0 = blockIdx.x * 16;
  int lbA = row0 >> 8, mA0 = row0 & 255;
  for (int i = tid; i < HID_ * H_; i += 256) { wa_lds[i] = Wa[i]; wg_lds[i] = Wg[i]; }
  for (int i = tid; i < 16 * H_; i += 256) {
    int r = i / H_, j = i - r * H_;
    int row = row0 + r;
    int lb = row >> 8, m = row & 255;
    int l = lb >> 3, b = lb & 7;
    x_lds[r][j] = x[((b * L_ + l) * M_ + m) * H_ + j];
  }
  __syncthreads();
  int lane = tid & 63, wv = tid >> 6;
  float aA[4], aS[4];
  float bav = ba[lane], bgv = bg[lane];
  #pragma unroll
  for (int ri = 0; ri < 4; ++ri) { aA[ri] = bav; aS[ri] = bgv; }
  for (int j = 0; j < H_; ++j) {
    float wa = wa_lds[lane * H_ + j];
    float wg = wg_lds[lane * H_ + j];
    #pragma unroll
    for (int ri = 0; ri < 4; ++ri) {
      float xv = x_lds[wv * 4 + ri][j];
      aA[ri] = fmaf(xv, wa, aA[ri]);
      aS[ri] = fmaf(xv, wg, aS[ri]);
    }
  }
  #pragma unroll
  for (int ri = 0; ri < 4; ++ri) {
    int row = row0 + wv * 4 + ri;
    a_lin_bf[row * HID_ + lane] = f2bf(aA[ri]);
    s_sh[wv * 4 + ri][lane] = aS[ri];
    s_b[row * HID_ + lane] = f2bf(aS[ri]);
  }
  __syncthreads();
  // sT write: thread (e = tid>>2, m4 = tid&3) writes 4 consecutive m for its e
  {
    int e = tid >> 2, m4 = tid & 3;
    ushort4 v;
    v.x = f2bf(s_sh[m4 * 4 + 0][e]);
    v.y = f2bf(s_sh[m4 * 4 + 1][e]);
    v.z = f2bf(s_sh[m4 * 4 + 2][e]);
    v.w = f2bf(s_sh[m4 * 4 + 3][e]);
    *(ushort4*)&sT_b[(lbA * 64 + e) * 256 + mA0 + m4 * 4] = v;
  }
  float aq[4] = {0.f, 0.f, 0.f, 0.f}, ak[4] = {0.f, 0.f, 0.f, 0.f};
  for (int j = 0; j < HID_; ++j) {
    float qw = Qw[j * HID_ + lane];
    float kw = Kw[j * HID_ + lane];
    #pragma unroll
    for (int ri = 0; ri < 4; ++ri) {
      float sv = s_sh[wv * 4 + ri][j];
      aq[ri] = fmaf(sv, qw, aq[ri]);
      ak[ri] = fmaf(sv, kw, ak[ri]);
    }
  }
  #pragma unroll
  for (int ri = 0; ri < 4; ++ri) {
    int row = row0 + wv * 4 + ri;
    q_b[row * HID_ + lane] = f2bf(aq[ri] * 0.08838834764831845f);  // fold 1/sqrt(128)
    k_b[row * HID_ + lane] = f2bf(ak[ri]);
  }
  // one-time duties
  if (blockIdx.x < 256) {
    int l = blockIdx.x;
    int gv = Gmat[l * 256 + tid];
    unsigned long long msk = __ballot(gv > 0);
    if ((tid & 63) == 0) {
      gmask[l * 8 + (tid >> 6) * 2] = (unsigned)msk;
      gmask[l * 8 + (tid >> 6) * 2 + 1] = (unsigned)(msk >> 32);
    }
  } else if (blockIdx.x < 512) {
    int n = blockIdx.x - 256;
    if (tid < 128) {
      float acc = 0.f;
      for (int e = 0; e < 64; ++e) acc = fmaf(Wih_c[n * 64 + e], W2[e * 128 + tid], acc);
      Wfold_b[n * 128 + tid] = f2bf(acc);
      if (tid == 0) {
        float bacc = 0.f;
        for (int e = 0; e < 64; ++e) bacc = fmaf(Wih_c[n * 64 + e], b2[e], bacc);
        bias_fold[n] = bacc;
      }
    }
  }
}

// ---------------- Kernel B: LDS-free streaming MFMA attention ----------------
// 512 blocks (lb, quarter) x 512 threads (8 waves); wave = 16 l-rows x 2 heads.
__global__ __launch_bounds__(512, 4) void kB_attn(
    const unsigned short* __restrict__ qb, const unsigned short* __restrict__ kb,
    const unsigned short* __restrict__ sT, const unsigned* __restrict__ gmask,
    unsigned short* __restrict__ so_b) {
  int blk = blockIdx.x;
  int lb = blk >> 2;
  int l0 = (blk & 3) << 6;
  int tid = threadIdx.x;
  int lane = tid & 63, w = tid >> 6;
  int c16 = lane & 15, q4 = lane >> 4;
  int lrow0 = (w >> 1) * 16;
  int h0 = (w & 1) * 2;
  int lrow = lb * 256 + l0 + lrow0;   // global q-row base
  int kbase = lb * 256;
  const bf16x8 z8 = {0, 0, 0, 0, 0, 0, 0, 0};
  bf16x8 bq[2];
  #pragma unroll
  for (int hp = 0; hp < 2; ++hp) {
    int h = h0 + hp;
    bq[hp] = (q4 < 2) ? *(const bf16x8*)(qb + (lrow + c16) * 64 + h * 16 + q4 * 8) : z8;
  }
  unsigned gwv[8];
  #pragma unroll
  for (int sp = 0; sp < 8; ++sp) gwv[sp] = gmask[(l0 + lrow0 + c16) * 8 + sp];
  f32x4 accO[2];
  float sumh[2];
  #pragma unroll
  for (int hp = 0; hp < 2; ++hp) { accO[hp] = (f32x4){0.f, 0.f, 0.f, 0.f}; sumh[hp] = 0.f; }

  #pragma unroll
  for (int sp = 0; sp < 8; ++sp) {
    unsigned gw = gwv[sp];
    #pragma unroll
    for (int hp = 0; hp < 2; ++hp) {
      int h = h0 + hp;
      unsigned pk0A, pk1A, pk0B, pk1B;
      #pragma unroll
      for (int tp = 0; tp < 2; ++tp) {
        int t = sp * 2 + tp;
        bf16x8 ka = z8;
        if (q4 < 2) ka = *(const bf16x8*)(kb + (kbase + t * 16 + c16) * 64 + h * 16 + q4 * 8);
        f32x4 d = __builtin_amdgcn_mfma_f32_16x16x32_bf16(ka, bq[hp], (f32x4){0.f, 0.f, 0.f, 0.f}, 0, 0, 0);
        int bitbase = tp * 16 + q4 * 4;
        float p0 = ((gw >> (bitbase + 0)) & 1u) ? __expf(d[0]) : 0.f;
        float p1 = ((gw >> (bitbase + 1)) & 1u) ? __expf(d[1]) : 0.f;
        float p2 = ((gw >> (bitbase + 2)) & 1u) ? __expf(d[2]) : 0.f;
        float p3 = ((gw >> (bitbase + 3)) & 1u) ? __expf(d[3]) : 0.f;
        sumh[hp] += (p0 + p1) + (p2 + p3);
        unsigned lo = (unsigned)f2bf(p0) | ((unsigned)f2bf(p1) << 16);
        unsigned hi = (unsigned)f2bf(p2) | ((unsigned)f2bf(p3) << 16);
        if (tp == 0) { pk0A = lo; pk1A = hi; } else { pk0B = lo; pk1B = hi; }
      }
      int srcA = ((q4 & 1) * 2) * 16 + c16, srcB = srcA + 16;
      unsigned g0A = (unsigned)__shfl((int)pk0A, srcA);
      unsigned g1A = (unsigned)__shfl((int)pk1A, srcA);
      unsigned g2A = (unsigned)__shfl((int)pk0A, srcB);
      unsigned g3A = (unsigned)__shfl((int)pk1A, srcB);
      unsigned g0B = (unsigned)__shfl((int)pk0B, srcA);
      unsigned g1B = (unsigned)__shfl((int)pk1B, srcA);
      unsigned g2B = (unsigned)__shfl((int)pk0B, srcB);
      unsigned g3B = (unsigned)__shfl((int)pk1B, srcB);
      bool useB = (q4 >= 2);
      uint4 av;
      av.x = useB ? g0B : g0A;
      av.y = useB ? g1B : g1A;
      av.z = useB ? g2B : g2A;
      av.w = useB ? g3B : g3A;
      bf16x8 af = __builtin_bit_cast(bf16x8, av);
      bf16x8 bs = *(const bf16x8*)(sT + (lb * 64 + h * 16 + c16) * 256 + sp * 32 + q4 * 8);
      accO[hp] = __builtin_amdgcn_mfma_f32_16x16x32_bf16(af, bs, accO[hp], 0, 0, 0);
    }
  }
  #pragma unroll
  for (int hp = 0; hp < 2; ++hp) {
    int h = h0 + hp;
    float s = sumh[hp];
    s += __shfl_xor(s, 16);
    s += __shfl_xor(s, 32);
    #pragma unroll
    for (int r = 0; r < 4; ++r) {
      float sv = __shfl(s, q4 * 4 + r);
      float o = accO[hp][r] / sv;
      so_b[(lb * 256 + l0 + lrow0 + q4 * 4 + r) * 64 + h * 16 + c16] = f2bf(o);
    }
  }
}

// ---------------- kR: merged LSTM (gates from inputs + recurrence, both LSTMs) ----------------
#define LSTM_EPILOGUE(BSV)                                                     \
  {                                                                            \
    float4 gi4 = *(const float4*)&gates_lds[useq * 264 + hidb];                \
    float4 gf4 = *(const float4*)&gates_lds[useq * 264 + 64 + hidb];           \
    float4 gg4 = *(const float4*)&gates_lds[useq * 264 + 128 + hidb];          \
    float4 go4 = *(const float4*)&gates_lds[useq * 264 + 192 + hidb];          \
    float gi[4] = {gi4.x + BSV[0].x, gi4.y + BSV[0].y, gi4.z + BSV[0].z, gi4.w + BSV[0].w}; \
    float gf[4] = {gf4.x + BSV[1].x, gf4.y + BSV[1].y, gf4.z + BSV[1].z, gf4.w + BSV[1].w}; \
    float gg[4] = {gg4.x + BSV[2].x, gg4.y + BSV[2].y, gg4.z + BSV[2].z, gg4.w + BSV[2].w}; \
    float go[4] = {go4.x + BSV[3].x, go4.y + BSV[3].y, go4.z + BSV[3].z, go4.w + BSV[3].w}; \
    unsigned short hb[4];                                                      \
    _Pragma("unroll")                                                          \
    for (int e = 0; e < 4; ++e) {                                              \
      float si = 1.f / (1.f + __expf(-gi[e]));                                 \
      float sf = 1.f / (1.f + __expf(-gf[e]));                                 \
      float so = 1.f / (1.f + __expf(-go[e]));                                 \
      cr[e] = sf * cr[e] + si * tanhf(gg[e]);                                  \
      hv[e] = so * tanhf(cr[e]);                                               \
      hb[e] = f2bf(hv[e]);                                                     \
    }                                                                          \
    unsigned hp0 = (unsigned)hb[0] | ((unsigned)hb[1] << 16);                  \
    unsigned hp1 = (unsigned)hb[2] | ((unsigned)hb[3] << 16);                  \
    *(uint2*)&h_lds[useq * 72 + hidb] = make_uint2(hp0, hp1);                  \
  }

__global__ __launch_bounds__(256, 1) void kR_lstm(
    const unsigned short* __restrict__ a_lin_bf,
    const unsigned short* __restrict__ s_b, const unsigned short* __restrict__ so_b,
    const unsigned short* __restrict__ Wfold_b, const float* __restrict__ bias_fold,
    const float* __restrict__ Wih_a,
    const float* __restrict__ Whh_a, const float* __restrict__ Whh_c,
    const float* __restrict__ bih_a, const float* __restrict__ bhh_a,
    const float* __restrict__ bih_c, const float* __restrict__ bhh_c,
    float* __restrict__ ah, float* __restrict__ ch) {
  int blk = blockIdx.x;
  int which = blk >> 7, g = blk & 127;
  int seq0 = g * 16;
  int b = seq0 >> 8, m0 = seq0 & 255;
  __shared__ __attribute__((aligned(16))) unsigned short h_lds[16 * 72];
  __shared__ __attribute__((aligned(16))) float gates_lds[16 * 264];
  int tid = threadIdx.x;
  int lane = tid & 63, w = tid >> 6;
  int c16 = lane & 15, q4 = lane >> 4;
  int n0 = w * 64;
  int useq = tid >> 4, hidb = (tid & 15) * 4;
  const float* bih = which ? bih_c : bih_a;
  const float* bhh = which ? bhh_c : bhh_a;
  float4 bsv[4];
  #pragma unroll
  for (int gi = 0; gi < 4; ++gi) {
    float4 u = *(const float4*)&bih[gi * 64 + hidb];
    float4 v = *(const float4*)&bhh[gi * 64 + hidb];
    bsv[gi] = make_float4(u.x + v.x, u.y + v.y, u.z + v.z, u.w + v.w);
    if (which) {
      float4 bf4 = *(const float4*)&bias_fold[gi * 64 + hidb];
      bsv[gi].x += bf4.x; bsv[gi].y += bf4.y; bsv[gi].z += bf4.z; bsv[gi].w += bf4.w;
    }
  }
  const float* Whh = which ? Whh_c : Whh_a;
  bf16x8 bwhh[4][2];
  #pragma unroll
  for (int nt = 0; nt < 4; ++nt) {
    #pragma unroll
    for (int kf = 0; kf < 2; ++kf) {
      const float* wp = Whh + (n0 + nt * 16 + c16) * 64 + kf * 32 + q4 * 8;
      bf16x8 bb;
      #pragma unroll
      for (int j = 0; j < 8; ++j) bb[j] = (short)f2bf(wp[j]);
      bwhh[nt][kf] = bb;
    }
  }
  *(uint2*)&h_lds[useq * 72 + hidb] = make_uint2(0u, 0u);
  float cr[4] = {0.f, 0.f, 0.f, 0.f};
  float hv[4] = {0.f, 0.f, 0.f, 0.f};
  __syncthreads();

  const int STEP = 2048 * 64;  // row stride per timestep (ushorts)
  if (which == 0) {
    // ---- actor ----
    bf16x8 bwin[4][2];
    #pragma unroll
    for (int nt = 0; nt < 4; ++nt) {
      #pragma unroll
      for (int kf = 0; kf < 2; ++kf) {
        const float* wp = Wih_a + (n0 + nt * 16 + c16) * 64 + kf * 32 + q4 * 8;
        bf16x8 bb;
        #pragma unroll
        for (int j = 0; j < 8; ++j) bb[j] = (short)f2bf(wp[j]);
        bwin[nt][kf] = bb;
      }
    }
    const unsigned short* inb = a_lin_bf + (b * 256 + m0 + c16) * 64;
    bf16x8 i0c = *(const bf16x8*)(inb + q4 * 8);
    bf16x8 i1c = *(const bf16x8*)(inb + 32 + q4 * 8);
    #pragma unroll
    for (int l = 0; l < L_; ++l) {
      bf16x8 i0n = i0c, i1n = i1c;
      if (l < L_ - 1) {
        i0n = *(const bf16x8*)(inb + (l + 1) * STEP + q4 * 8);
        i1n = *(const bf16x8*)(inb + (l + 1) * STEP + 32 + q4 * 8);
      }
      bf16x8 ah0 = *(const bf16x8*)&h_lds[c16 * 72 + q4 * 8];
      bf16x8 ah1 = *(const bf16x8*)&h_lds[c16 * 72 + 32 + q4 * 8];
      #pragma unroll
      for (int nt = 0; nt < 4; ++nt) {
        f32x4 acc = {0.f, 0.f, 0.f, 0.f};
        acc = __builtin_amdgcn_mfma_f32_16x16x32_bf16(i0c, bwin[nt][0], acc, 0, 0, 0);
        acc = __builtin_amdgcn_mfma_f32_16x16x32_bf16(i1c, bwin[nt][1], acc, 0, 0, 0);
        acc = __builtin_amdgcn_mfma_f32_16x16x32_bf16(ah0, bwhh[nt][0], acc, 0, 0, 0);
        acc = __builtin_amdgcn_mfma_f32_16x16x32_bf16(ah1, bwhh[nt][1], acc, 0, 0, 0);
        #pragma unroll
        for (int rr = 0; rr < 4; ++rr)
          gates_lds[(q4 * 4 + rr) * 264 + n0 + nt * 16 + c16] = acc[rr];
      }
      __syncthreads();
      LSTM_EPILOGUE(bsv);
      __syncthreads();
      i0c = i0n; i1c = i1n;
    }
    *(float4*)&ah[(seq0 + useq) * 64 + hidb] = make_float4(hv[0], hv[1], hv[2], hv[3]);
  } else {
    // ---- critic: in = [s | so] (K=128) vs Wfold ----
    bf16x8 bwf[4][4];
    #pragma unroll
    for (int nt = 0; nt < 4; ++nt) {
      #pragma unroll
      for (int kc = 0; kc < 4; ++kc) {
        bwf[nt][kc] = *(const bf16x8*)(Wfold_b + (n0 + nt * 16 + c16) * 128 + kc * 32 + q4 * 8);
      }
    }
    const unsigned short* sbB = s_b + (b * 256 + m0 + c16) * 64;
    const unsigned short* soB = so_b + (b * 256 + m0 + c16) * 64;
    bf16x8 s0c = *(const bf16x8*)(sbB + q4 * 8);
    bf16x8 s1c = *(const bf16x8*)(sbB + 32 + q4 * 8);
    bf16x8 o0c = *(const bf16x8*)(soB + q4 * 8);
    bf16x8 o1c = *(const bf16x8*)(soB + 32 + q4 * 8);
    #pragma unroll
    for (int l = 0; l < L_; ++l) {
      bf16x8 s0n = s0c, s1n = s1c, o0n = o0c, o1n = o1c;
      if (l < L_ - 1) {
        s0n = *(const bf16x8*)(sbB + (l + 1) * STEP + q4 * 8);
        s1n = *(const bf16x8*)(sbB + (l + 1) * STEP + 32 + q4 * 8);
        o0n = *(const bf16x8*)(soB + (l + 1) * STEP + q4 * 8);
        o1n = *(const bf16x8*)(soB + (l + 1) * STEP + 32 + q4 * 8);
      }
      bf16x8 ah0 = *(const bf16x8*)&h_lds[c16 * 72 + q4 * 8];
      bf16x8 ah1 = *(const bf16x8*)&h_lds[c16 * 72 + 32 + q4 * 8];
      #pragma unroll
      for (int nt = 0; nt < 4; ++nt) {
        f32x4 acc = {0.f, 0.f, 0.f, 0.f};
        acc = __builtin_amdgcn_mfma_f32_16x16x32_bf16(s0c, bwf[nt][0], acc, 0, 0, 0);
        acc = __builtin_amdgcn_mfma_f32_16x16x32_bf16(s1c, bwf[nt][1], acc, 0, 0, 0);
        acc = __builtin_amdgcn_mfma_f32_16x16x32_bf16(o0c, bwf[nt][2], acc, 0, 0, 0);
        acc = __builtin_amdgcn_mfma_f32_16x16x32_bf16(o1c, bwf[nt][3], acc, 0, 0, 0);
        acc = __builtin_amdgcn_mfma_f32_16x16x32_bf16(ah0, bwhh[nt][0], acc, 0, 0, 0);
        acc = __builtin_amdgcn_mfma_f32_16x16x32_bf16(ah1, bwhh[nt][1], acc, 0, 0, 0);
        #pragma unroll
        for (int rr = 0; rr < 4; ++rr)
          gates_lds[(q4 * 4 + rr) * 264 + n0 + nt * 16 + c16] = acc[rr];
      }
      __syncthreads();
      LSTM_EPILOGUE(bsv);
      __syncthreads();
      s0c = s0n; s1c = s1n; o0c = o0n; o1c = o1n;
    }
    *(float4*)&ch[(seq0 + useq) * 64 + hidb] = make_float4(hv[0], hv[1], hv[2], hv[3]);
  }
}

// ---------------- K5: heads + outputs ----------------
__global__ __launch_bounds__(64) void k5_heads(const float* __restrict__ ah,
    const float* __restrict__ ch, const int* __restrict__ action,
    const float* __restrict__ Wma1, const float* __restrict__ bma1,
    const float* __restrict__ Wma2, const float* __restrict__ bma2,
    const float* __restrict__ Wmc1, const float* __restrict__ bmc1,
    const float* __restrict__ Wmc2, const float* __restrict__ bmc2,
    float* __restrict__ out) {
  int n = blockIdx.x;
  int t = threadIdx.x;
  __shared__ float ha[HID_], hc[HID_], hA[HID_], logit[15], grp[6];
  ha[t] = ah[n * HID_ + t];
  hc[t] = ch[n * HID_ + t];
  __syncthreads();
  float aA = bma1[t], aC = bmc1[t];
  #pragma unroll
  for (int j = 0; j < HID_; ++j) {
    aA = fmaf(ha[j], Wma1[t * HID_ + j], aA);
    aC = fmaf(hc[j], Wmc1[t * HID_ + j], aC);
  }
  float hCt = tanhf(aC);
  hA[t] = tanhf(aA);
  __syncthreads();
  float pv = hCt * Wmc2[t];
  #pragma unroll
  for (int off = 32; off > 0; off >>= 1) pv += __shfl_xor(pv, off);
  if (t < 15) {
    float acc = bma2[t];
    #pragma unroll
    for (int j = 0; j < HID_; ++j) acc = fmaf(hA[j], Wma2[t * HID_ + j], acc);
    logit[t] = acc;
  }
  __syncthreads();
  if (t < 3) {
    float l0 = logit[t * 5 + 0], l1 = logit[t * 5 + 1], l2 = logit[t * 5 + 2];
    float l3 = logit[t * 5 + 3], l4 = logit[t * 5 + 4];
    float mx = fmaxf(fmaxf(fmaxf(l0, l1), fmaxf(l2, l3)), l4);
    float sm = expf(l0 - mx) + expf(l1 - mx) + expf(l2 - mx) + expf(l3 - mx) + expf(l4 - mx);
    float lse = logf(sm) + mx;
    int a = action[n * 3 + t];
    float lp0 = l0 - lse, lp1 = l1 - lse, lp2 = l2 - lse, lp3 = l3 - lse, lp4 = l4 - lse;
    float lpsel = logit[t * 5 + a] - lse;
    float ent = -(expf(lp0) * lp0 + expf(lp1) * lp1 + expf(lp2) * lp2 +
                  expf(lp3) * lp3 + expf(lp4) * lp4);
    grp[t] = lpsel;
    grp[3 + t] = ent;
    out[n * 3 + t] = (float)a;
  }
  __syncthreads();
  if (t == 0) {
    out[6144 + n] = grp[0] + grp[1] + grp[2];
    out[8192 + n] = grp[3] + grp[4] + grp[5];
    out[10240 + n] = pv + bmc2[0];
  }
}

extern "C" void kernel_launch(void* const* d_in, const int* in_sizes, int n_in,
                              void* d_out, int out_size, void* d_ws, size_t ws_size,
                              hipStream_t stream) {
  const float* x_actor = (const float*)d_in[0];
  const int* action = (const int*)d_in[2];
  const int* Gmat  = (const int*)d_in[3];
  const float* Wa = (const float*)d_in[4];  const float* ba = (const float*)d_in[5];
  const float* Wg = (const float*)d_in[6];  const float* bg = (const float*)d_in[7];
  const float* Qw = (const float*)d_in[8];  const float* Kw = (const float*)d_in[9];
  const float* W2 = (const float*)d_in[10]; const float* b2 = (const float*)d_in[11];
  const float* Wih_a = (const float*)d_in[12]; const float* Whh_a = (const float*)d_in[13];
  const float* bih_a = (const float*)d_in[14]; const float* bhh_a = (const float*)d_in[15];
  const float* Wih_c = (const float*)d_in[16]; const float* Whh_c = (const float*)d_in[17];
  const float* bih_c = (const float*)d_in[18]; const float* bhh_c = (const float*)d_in[19];
  const float* Wma1 = (const float*)d_in[20]; const float* bma1 = (const float*)d_in[21];
  const float* Wma2 = (const float*)d_in[22]; const float* bma2 = (const float*)d_in[23];
  const float* Wmc1 = (const float*)d_in[24]; const float* bmc1 = (const float*)d_in[25];
  const float* Wmc2 = (const float*)d_in[26]; const float* bmc2 = (const float*)d_in[27];

  unsigned short* us = (unsigned short*)d_ws;
  unsigned short* a_lin_bf = us;                 // 2,097,152
  unsigned short* s_b  = us + 2097152;           // 2,097,152
  unsigned short* q_b  = us + 4194304;
  unsigned short* k_b  = us + 6291456;
  unsigned short* sT_b = us + 8388608;           // 2,097,152 (128 lb x 64 e x 256 m)
  unsigned short* so_b = us + 10485760;          // 2,097,152
  unsigned short* Wfold_b = us + 12582912;       // 32,768
  float* fb = (float*)(us + 12615680);           // byte off 25,231,360 (16B aligned)
  float* bias_fold = fb;                         // 256
  float* ah = fb + 256;                          // 131,072
  float* ch = fb + 131328;                       // 131,072
  unsigned* gmask = (unsigned*)(fb + 262400);    // 2,048
  float* out = (float*)d_out;

  kA_lin<<<2048, 256, 0, stream>>>(x_actor, Wa, ba, Wg, bg, Qw, Kw,
                                   Gmat, Wih_c, W2, b2,
                                   a_lin_bf, s_b, q_b, k_b, sT_b, Wfold_b,
                                   bias_fold, gmask);
  kB_attn<<<512, 512, 0, stream>>>(q_b, k_b, sT_b, gmask, so_b);
  kR_lstm<<<256, 256, 0, stream>>>(a_lin_bf, s_b, so_b, Wfold_b, bias_fold,
                                   Wih_a, Whh_a, Whh_c, bih_a, bhh_a, bih_c, bhh_c,
                                   ah, ch);
  k5_heads<<<2048, 64, 0, stream>>>(ah, ch, action, Wma1, bma1, Wma2, bma2,
                                    Wmc1, bmc1, Wmc2, bmc2, out);
}

// Round 5
// 79.407 us; speedup vs baseline: 8.5704x; 1.3217x over previous
//
#include <hip/hip_runtime.h>
#include <math.h>

#define B_ 8
#define L_ 16
#define M_ 256
#define H_ 53
#define HID_ 64
#define LB_ 128  // L_*B_

typedef __attribute__((ext_vector_type(8))) short bf16x8;
typedef __attribute__((ext_vector_type(4))) float f32x4;

__device__ inline unsigned short f2bf(float f) {
  unsigned u = __builtin_bit_cast(unsigned, f);
  unsigned r = (u + 0x7FFFu + ((u >> 16) & 1u)) >> 16;
  return (unsigned short)r;
}
// fast sigmoid / tanh via hw exp+rcp (rel err ~1e-6, tolerance is 9.75e-2)
__device__ inline float sigm(float x) { return __builtin_amdgcn_rcpf(1.f + __expf(-x)); }
__device__ inline float ftanh(float x) { return 1.f - 2.f * __builtin_amdgcn_rcpf(1.f + __expf(2.f * x)); }

// ---------------- Kernel A: fused a_lin/s + q/k + sT + (gmask, Wfold duties) ----------------
__global__ __launch_bounds__(256) void kA_lin(const float* __restrict__ x,
    const float* __restrict__ Wa, const float* __restrict__ ba,
    const float* __restrict__ Wg, const float* __restrict__ bg,
    const float* __restrict__ Qw, const float* __restrict__ Kw,
    const int* __restrict__ Gmat, const float* __restrict__ Wih_c,
    const float* __restrict__ W2, const float* __restrict__ b2,
    unsigned short* __restrict__ a_lin_bf, unsigned short* __restrict__ s_b,
    unsigned short* __restrict__ q_b, unsigned short* __restrict__ k_b,
    unsigned short* __restrict__ sT_b, unsigned short* __restrict__ Wfold_b,
    float* __restrict__ bias_fold, unsigned* __restrict__ gmask) {
  __shared__ float wa_lds[HID_ * H_];
  __shared__ float wg_lds[HID_ * H_];
  __shared__ float x_lds[16][H_];
  __shared__ float s_sh[16][HID_];
  int tid = threadIdx.x;
  int row0 = blockIdx.x * 16;
  int lbA = row0 >> 8, mA0 = row0 & 255;
  for (int i = tid; i < HID_ * H_; i += 256) { wa_lds[i] = Wa[i]; wg_lds[i] = Wg[i]; }
  for (int i = tid; i < 16 * H_; i += 256) {
    int r = i / H_, j = i - r * H_;
    int row = row0 + r;
    int lb = row >> 8, m = row & 255;
    int l = lb >> 3, b = lb & 7;
    x_lds[r][j] = x[((b * L_ + l) * M_ + m) * H_ + j];
  }
  __syncthreads();
  int lane = tid & 63, wv = tid >> 6;
  float aA[4], aS[4];
  float bav = ba[lane], bgv = bg[lane];
  #pragma unroll
  for (int ri = 0; ri < 4; ++ri) { aA[ri] = bav; aS[ri] = bgv; }
  for (int j = 0; j < H_; ++j) {
    float wa = wa_lds[lane * H_ + j];
    float wg = wg_lds[lane * H_ + j];
    #pragma unroll
    for (int ri = 0; ri < 4; ++ri) {
      float xv = x_lds[wv * 4 + ri][j];
      aA[ri] = fmaf(xv, wa, aA[ri]);
      aS[ri] = fmaf(xv, wg, aS[ri]);
    }
  }
  #pragma unroll
  for (int ri = 0; ri < 4; ++ri) {
    int row = row0 + wv * 4 + ri;
    a_lin_bf[row * HID_ + lane] = f2bf(aA[ri]);
    s_sh[wv * 4 + ri][lane] = aS[ri];
    s_b[row * HID_ + lane] = f2bf(aS[ri]);
  }
  __syncthreads();
  // sT write: thread (e = tid>>2, m4 = tid&3) writes 4 consecutive m for its e
  {
    int e = tid >> 2, m4 = tid & 3;
    ushort4 v;
    v.x = f2bf(s_sh[m4 * 4 + 0][e]);
    v.y = f2bf(s_sh[m4 * 4 + 1][e]);
    v.z = f2bf(s_sh[m4 * 4 + 2][e]);
    v.w = f2bf(s_sh[m4 * 4 + 3][e]);
    *(ushort4*)&sT_b[(lbA * 64 + e) * 256 + mA0 + m4 * 4] = v;
  }
  float aq[4] = {0.f, 0.f, 0.f, 0.f}, ak[4] = {0.f, 0.f, 0.f, 0.f};
  for (int j = 0; j < HID_; ++j) {
    float qw = Qw[j * HID_ + lane];
    float kw = Kw[j * HID_ + lane];
    #pragma unroll
    for (int ri = 0; ri < 4; ++ri) {
      float sv = s_sh[wv * 4 + ri][j];
      aq[ri] = fmaf(sv, qw, aq[ri]);
      ak[ri] = fmaf(sv, kw, ak[ri]);
    }
  }
  #pragma unroll
  for (int ri = 0; ri < 4; ++ri) {
    int row = row0 + wv * 4 + ri;
    q_b[row * HID_ + lane] = f2bf(aq[ri] * 0.08838834764831845f);  // fold 1/sqrt(128)
    k_b[row * HID_ + lane] = f2bf(ak[ri]);
  }
  // one-time duties
  if (blockIdx.x < 256) {
    int l = blockIdx.x;
    int gv = Gmat[l * 256 + tid];
    unsigned long long msk = __ballot(gv > 0);
    if ((tid & 63) == 0) {
      gmask[l * 8 + (tid >> 6) * 2] = (unsigned)msk;
      gmask[l * 8 + (tid >> 6) * 2 + 1] = (unsigned)(msk >> 32);
    }
  } else if (blockIdx.x < 512) {
    int n = blockIdx.x - 256;
    if (tid < 128) {
      float acc = 0.f;
      for (int e = 0; e < 64; ++e) acc = fmaf(Wih_c[n * 64 + e], W2[e * 128 + tid], acc);
      Wfold_b[n * 128 + tid] = f2bf(acc);
      if (tid == 0) {
        float bacc = 0.f;
        for (int e = 0; e < 64; ++e) bacc = fmaf(Wih_c[n * 64 + e], b2[e], bacc);
        bias_fold[n] = bacc;
      }
    }
  }
}

// ---------------- Kernel B: LDS-free streaming MFMA attention ----------------
__global__ __launch_bounds__(512, 4) void kB_attn(
    const unsigned short* __restrict__ qb, const unsigned short* __restrict__ kb,
    const unsigned short* __restrict__ sT, const unsigned* __restrict__ gmask,
    unsigned short* __restrict__ so_b) {
  int blk = blockIdx.x;
  int lb = blk >> 2;
  int l0 = (blk & 3) << 6;
  int tid = threadIdx.x;
  int lane = tid & 63, w = tid >> 6;
  int c16 = lane & 15, q4 = lane >> 4;
  int lrow0 = (w >> 1) * 16;
  int h0 = (w & 1) * 2;
  int lrow = lb * 256 + l0 + lrow0;
  int kbase = lb * 256;
  const bf16x8 z8 = {0, 0, 0, 0, 0, 0, 0, 0};
  bf16x8 bq[2];
  #pragma unroll
  for (int hp = 0; hp < 2; ++hp) {
    int h = h0 + hp;
    bq[hp] = (q4 < 2) ? *(const bf16x8*)(qb + (lrow + c16) * 64 + h * 16 + q4 * 8) : z8;
  }
  unsigned gwv[8];
  #pragma unroll
  for (int sp = 0; sp < 8; ++sp) gwv[sp] = gmask[(l0 + lrow0 + c16) * 8 + sp];
  f32x4 accO[2];
  float sumh[2];
  #pragma unroll
  for (int hp = 0; hp < 2; ++hp) { accO[hp] = (f32x4){0.f, 0.f, 0.f, 0.f}; sumh[hp] = 0.f; }

  #pragma unroll
  for (int sp = 0; sp < 8; ++sp) {
    unsigned gw = gwv[sp];
    #pragma unroll
    for (int hp = 0; hp < 2; ++hp) {
      int h = h0 + hp;
      unsigned pk0A, pk1A, pk0B, pk1B;
      #pragma unroll
      for (int tp = 0; tp < 2; ++tp) {
        int t = sp * 2 + tp;
        bf16x8 ka = z8;
        if (q4 < 2) ka = *(const bf16x8*)(kb + (kbase + t * 16 + c16) * 64 + h * 16 + q4 * 8);
        f32x4 d = __builtin_amdgcn_mfma_f32_16x16x32_bf16(ka, bq[hp], (f32x4){0.f, 0.f, 0.f, 0.f}, 0, 0, 0);
        int bitbase = tp * 16 + q4 * 4;
        float p0 = ((gw >> (bitbase + 0)) & 1u) ? __expf(d[0]) : 0.f;
        float p1 = ((gw >> (bitbase + 1)) & 1u) ? __expf(d[1]) : 0.f;
        float p2 = ((gw >> (bitbase + 2)) & 1u) ? __expf(d[2]) : 0.f;
        float p3 = ((gw >> (bitbase + 3)) & 1u) ? __expf(d[3]) : 0.f;
        sumh[hp] += (p0 + p1) + (p2 + p3);
        unsigned lo = (unsigned)f2bf(p0) | ((unsigned)f2bf(p1) << 16);
        unsigned hi = (unsigned)f2bf(p2) | ((unsigned)f2bf(p3) << 16);
        if (tp == 0) { pk0A = lo; pk1A = hi; } else { pk0B = lo; pk1B = hi; }
      }
      int srcA = ((q4 & 1) * 2) * 16 + c16, srcB = srcA + 16;
      unsigned g0A = (unsigned)__shfl((int)pk0A, srcA);
      unsigned g1A = (unsigned)__shfl((int)pk1A, srcA);
      unsigned g2A = (unsigned)__shfl((int)pk0A, srcB);
      unsigned g3A = (unsigned)__shfl((int)pk1A, srcB);
      unsigned g0B = (unsigned)__shfl((int)pk0B, srcA);
      unsigned g1B = (unsigned)__shfl((int)pk1B, srcA);
      unsigned g2B = (unsigned)__shfl((int)pk0B, srcB);
      unsigned g3B = (unsigned)__shfl((int)pk1B, srcB);
      bool useB = (q4 >= 2);
      uint4 av;
      av.x = useB ? g0B : g0A;
      av.y = useB ? g1B : g1A;
      av.z = useB ? g2B : g2A;
      av.w = useB ? g3B : g3A;
      bf16x8 af = __builtin_bit_cast(bf16x8, av);
      bf16x8 bs = *(const bf16x8*)(sT + (lb * 64 + h * 16 + c16) * 256 + sp * 32 + q4 * 8);
      accO[hp] = __builtin_amdgcn_mfma_f32_16x16x32_bf16(af, bs, accO[hp], 0, 0, 0);
    }
  }
  #pragma unroll
  for (int hp = 0; hp < 2; ++hp) {
    int h = h0 + hp;
    float s = sumh[hp];
    s += __shfl_xor(s, 16);
    s += __shfl_xor(s, 32);
    #pragma unroll
    for (int r = 0; r < 4; ++r) {
      float sv = __shfl(s, q4 * 4 + r);
      float o = accO[hp][r] / sv;
      so_b[(lb * 256 + l0 + lrow0 + q4 * 4 + r) * 64 + h * 16 + c16] = f2bf(o);
    }
  }
}

// ---------------- kR: LSTM recurrence (1 barrier/step, in-register gates) + fused heads ----------------
// 256 blocks (which = blk>>7, 16 seqs each) x 256 threads (4 waves).
// Wave w owns hid-slice hs0=w*16 and computes gate tiles n = {hs0, 64+hs0, 128+hs0, 192+hs0}
// -> lane (c16,q4) holds i,f,g,o for (seq=q4*4+rr, hid=hs0+c16) IN REGISTERS.
__global__ __launch_bounds__(256, 1) void kR_lstm(
    const unsigned short* __restrict__ a_lin_bf,
    const unsigned short* __restrict__ s_b, const unsigned short* __restrict__ so_b,
    const unsigned short* __restrict__ Wfold_b, const float* __restrict__ bias_fold,
    const float* __restrict__ Wih_a,
    const float* __restrict__ Whh_a, const float* __restrict__ Whh_c,
    const float* __restrict__ bih_a, const float* __restrict__ bhh_a,
    const float* __restrict__ bih_c, const float* __restrict__ bhh_c,
    const int* __restrict__ action,
    const float* __restrict__ Wma1, const float* __restrict__ bma1,
    const float* __restrict__ Wma2, const float* __restrict__ bma2,
    const float* __restrict__ Wmc1, const float* __restrict__ bmc1,
    const float* __restrict__ Wmc2, const float* __restrict__ bmc2,
    float* __restrict__ out) {
  int blk = blockIdx.x;
  int which = blk >> 7, g = blk & 127;
  int seq0 = g * 16;
  int b = seq0 >> 8, m0 = seq0 & 255;
  __shared__ __attribute__((aligned(16))) unsigned short h_lds[2][16][72];
  __shared__ __attribute__((aligned(16))) unsigned short ha_lds[16][72];
  __shared__ float logit_lds[16][16];
  __shared__ float grp_lds[16][8];
  __shared__ float val_lds[16][4];
  int tid = threadIdx.x;
  int lane = tid & 63, w = tid >> 6;
  int c16 = lane & 15, q4 = lane >> 4;
  int hs0 = w * 16;
  const float* Whh = which ? Whh_c : Whh_a;
  const float* bih = which ? bih_c : bih_a;
  const float* bhh = which ? bhh_c : bhh_a;
  bf16x8 bwhh[4][2];
  float bias[4];
  #pragma unroll
  for (int nt = 0; nt < 4; ++nt) {
    int n = nt * 64 + hs0 + c16;
    bias[nt] = bih[n] + bhh[n] + (which ? bias_fold[n] : 0.f);
    #pragma unroll
    for (int kf = 0; kf < 2; ++kf) {
      const float* wp = Whh + n * 64 + kf * 32 + q4 * 8;
      bf16x8 bb;
      #pragma unroll
      for (int j = 0; j < 8; ++j) bb[j] = (short)f2bf(wp[j]);
      bwhh[nt][kf] = bb;
    }
  }
  // zero h buffer 0
  for (int i = tid; i < 576; i += 256) ((unsigned*)h_lds)[i] = 0u;
  float cr[4] = {0.f, 0.f, 0.f, 0.f};
  const int STEP = 2048 * 64;
  __syncthreads();
  int cur = 0;
  if (which == 0) {
    // ---- actor recurrence ----
    bf16x8 bwin[4][2];
    #pragma unroll
    for (int nt = 0; nt < 4; ++nt) {
      int n = nt * 64 + hs0 + c16;
      #pragma unroll
      for (int kf = 0; kf < 2; ++kf) {
        const float* wp = Wih_a + n * 64 + kf * 32 + q4 * 8;
        bf16x8 bb;
        #pragma unroll
        for (int j = 0; j < 8; ++j) bb[j] = (short)f2bf(wp[j]);
        bwin[nt][kf] = bb;
      }
    }
    const unsigned short* inb = a_lin_bf + (b * 256 + m0 + c16) * 64;
    bf16x8 i0c = *(const bf16x8*)(inb + q4 * 8);
    bf16x8 i1c = *(const bf16x8*)(inb + 32 + q4 * 8);
    for (int l = 0; l < L_; ++l) {
      bf16x8 i0n = i0c, i1n = i1c;
      if (l < L_ - 1) {
        i0n = *(const bf16x8*)(inb + (l + 1) * STEP + q4 * 8);
        i1n = *(const bf16x8*)(inb + (l + 1) * STEP + 32 + q4 * 8);
      }
      bf16x8 ah0 = *(const bf16x8*)&h_lds[cur][c16][q4 * 8];
      bf16x8 ah1 = *(const bf16x8*)&h_lds[cur][c16][32 + q4 * 8];
      f32x4 acc[4];
      #pragma unroll
      for (int nt = 0; nt < 4; ++nt) {
        f32x4 a = {bias[nt], bias[nt], bias[nt], bias[nt]};
        a = __builtin_amdgcn_mfma_f32_16x16x32_bf16(i0c, bwin[nt][0], a, 0, 0, 0);
        a = __builtin_amdgcn_mfma_f32_16x16x32_bf16(i1c, bwin[nt][1], a, 0, 0, 0);
        a = __builtin_amdgcn_mfma_f32_16x16x32_bf16(ah0, bwhh[nt][0], a, 0, 0, 0);
        a = __builtin_amdgcn_mfma_f32_16x16x32_bf16(ah1, bwhh[nt][1], a, 0, 0, 0);
        acc[nt] = a;
      }
      #pragma unroll
      for (int rr = 0; rr < 4; ++rr) {
        float si = sigm(acc[0][rr]);
        float sf = sigm(acc[1][rr]);
        float gg = ftanh(acc[2][rr]);
        float so_ = sigm(acc[3][rr]);
        cr[rr] = sf * cr[rr] + si * gg;
        float hvv = so_ * ftanh(cr[rr]);
        h_lds[cur ^ 1][q4 * 4 + rr][hs0 + c16] = f2bf(hvv);
      }
      __syncthreads();
      cur ^= 1;
      i0c = i0n; i1c = i1n;
    }
  } else {
    // ---- critic recurrence: in = [s | so] (K=128) vs Wfold ----
    bf16x8 bwf[4][4];
    #pragma unroll
    for (int nt = 0; nt < 4; ++nt) {
      int n = nt * 64 + hs0 + c16;
      #pragma unroll
      for (int kc = 0; kc < 4; ++kc) {
        bwf[nt][kc] = *(const bf16x8*)(Wfold_b + n * 128 + kc * 32 + q4 * 8);
      }
    }
    const unsigned short* sbB = s_b + (b * 256 + m0 + c16) * 64;
    const unsigned short* soB = so_b + (b * 256 + m0 + c16) * 64;
    bf16x8 s0c = *(const bf16x8*)(sbB + q4 * 8);
    bf16x8 s1c = *(const bf16x8*)(sbB + 32 + q4 * 8);
    bf16x8 o0c = *(const bf16x8*)(soB + q4 * 8);
    bf16x8 o1c = *(const bf16x8*)(soB + 32 + q4 * 8);
    for (int l = 0; l < L_; ++l) {
      bf16x8 s0n = s0c, s1n = s1c, o0n = o0c, o1n = o1c;
      if (l < L_ - 1) {
        s0n = *(const bf16x8*)(sbB + (l + 1) * STEP + q4 * 8);
        s1n = *(const bf16x8*)(sbB + (l + 1) * STEP + 32 + q4 * 8);
        o0n = *(const bf16x8*)(soB + (l + 1) * STEP + q4 * 8);
        o1n = *(const bf16x8*)(soB + (l + 1) * STEP + 32 + q4 * 8);
      }
      bf16x8 ah0 = *(const bf16x8*)&h_lds[cur][c16][q4 * 8];
      bf16x8 ah1 = *(const bf16x8*)&h_lds[cur][c16][32 + q4 * 8];
      f32x4 acc[4];
      #pragma unroll
      for (int nt = 0; nt < 4; ++nt) {
        f32x4 a = {bias[nt], bias[nt], bias[nt], bias[nt]};
        a = __builtin_amdgcn_mfma_f32_16x16x32_bf16(s0c, bwf[nt][0], a, 0, 0, 0);
        a = __builtin_amdgcn_mfma_f32_16x16x32_bf16(s1c, bwf[nt][1], a, 0, 0, 0);
        a = __builtin_amdgcn_mfma_f32_16x16x32_bf16(o0c, bwf[nt][2], a, 0, 0, 0);
        a = __builtin_amdgcn_mfma_f32_16x16x32_bf16(o1c, bwf[nt][3], a, 0, 0, 0);
        a = __builtin_amdgcn_mfma_f32_16x16x32_bf16(ah0, bwhh[nt][0], a, 0, 0, 0);
        a = __builtin_amdgcn_mfma_f32_16x16x32_bf16(ah1, bwhh[nt][1], a, 0, 0, 0);
        acc[nt] = a;
      }
      #pragma unroll
      for (int rr = 0; rr < 4; ++rr) {
        float si = sigm(acc[0][rr]);
        float sf = sigm(acc[1][rr]);
        float gg = ftanh(acc[2][rr]);
        float so_ = sigm(acc[3][rr]);
        cr[rr] = sf * cr[rr] + si * gg;
        float hvv = so_ * ftanh(cr[rr]);
        h_lds[cur ^ 1][q4 * 4 + rr][hs0 + c16] = f2bf(hvv);
      }
      __syncthreads();
      cur ^= 1;
      s0c = s0n; s1c = s1n; o0c = o0n; o1c = o1n;
    }
  }
  // ---- fused heads (h in h_lds[cur]) ----
  bf16x8 fh0 = *(const bf16x8*)&h_lds[cur][c16][q4 * 8];
  bf16x8 fh1 = *(const bf16x8*)&h_lds[cur][c16][32 + q4 * 8];
  if (which == 0) {
    // hA = tanh(h @ Wma1^T + bma1): wave w computes cols hs0..hs0+15
    bf16x8 bm1[2];
    #pragma unroll
    for (int kf = 0; kf < 2; ++kf) {
      const float* wp = Wma1 + (hs0 + c16) * 64 + kf * 32 + q4 * 8;
      bf16x8 bb;
      #pragma unroll
      for (int j = 0; j < 8; ++j) bb[j] = (short)f2bf(wp[j]);
      bm1[kf] = bb;
    }
    float bs = bma1[hs0 + c16];
    f32x4 acc = {bs, bs, bs, bs};
    acc = __builtin_amdgcn_mfma_f32_16x16x32_bf16(fh0, bm1[0], acc, 0, 0, 0);
    acc = __builtin_amdgcn_mfma_f32_16x16x32_bf16(fh1, bm1[1], acc, 0, 0, 0);
    #pragma unroll
    for (int rr = 0; rr < 4; ++rr)
      ha_lds[q4 * 4 + rr][hs0 + c16] = f2bf(ftanh(acc[rr]));
    __syncthreads();
    if (w == 0) {
      // logits (15 cols, wave 0 only)
      bf16x8 af0 = *(const bf16x8*)&ha_lds[c16][q4 * 8];
      bf16x8 af1 = *(const bf16x8*)&ha_lds[c16][32 + q4 * 8];
      const bf16x8 z8 = {0, 0, 0, 0, 0, 0, 0, 0};
      bf16x8 bw2[2] = {z8, z8};
      float bs2 = 0.f;
      if (c16 < 15) {
        #pragma unroll
        for (int kf = 0; kf < 2; ++kf) {
          const float* wp = Wma2 + c16 * 64 + kf * 32 + q4 * 8;
          bf16x8 bb;
          #pragma unroll
          for (int j = 0; j < 8; ++j) bb[j] = (short)f2bf(wp[j]);
          bw2[kf] = bb;
        }
        bs2 = bma2[c16];
      }
      f32x4 acc2 = {bs2, bs2, bs2, bs2};
      acc2 = __builtin_amdgcn_mfma_f32_16x16x32_bf16(af0, bw2[0], acc2, 0, 0, 0);
      acc2 = __builtin_amdgcn_mfma_f32_16x16x32_bf16(af1, bw2[1], acc2, 0, 0, 0);
      #pragma unroll
      for (int rr = 0; rr < 4; ++rr)
        logit_lds[q4 * 4 + rr][c16] = acc2[rr];
    }
    __syncthreads();
    if (tid < 48) {
      int useq = tid & 15, t = tid >> 4;
      int n = seq0 + useq;
      float l0 = logit_lds[useq][t * 5 + 0], l1 = logit_lds[useq][t * 5 + 1];
      float l2 = logit_lds[useq][t * 5 + 2], l3 = logit_lds[useq][t * 5 + 3];
      float l4 = logit_lds[useq][t * 5 + 4];
      float mx = fmaxf(fmaxf(fmaxf(l0, l1), fmaxf(l2, l3)), l4);
      float sm = __expf(l0 - mx) + __expf(l1 - mx) + __expf(l2 - mx) +
                 __expf(l3 - mx) + __expf(l4 - mx);
      float lse = __logf(sm) + mx;
      int a = action[n * 3 + t];
      float lp0 = l0 - lse, lp1 = l1 - lse, lp2 = l2 - lse, lp3 = l3 - lse, lp4 = l4 - lse;
      float lpsel = logit_lds[useq][t * 5 + a] - lse;
      float ent = -(__expf(lp0) * lp0 + __expf(lp1) * lp1 + __expf(lp2) * lp2 +
                    __expf(lp3) * lp3 + __expf(lp4) * lp4);
      grp_lds[useq][t] = lpsel;
      grp_lds[useq][4 + t] = ent;
      out[n * 3 + t] = (float)a;
    }
    __syncthreads();
    if (tid < 16) {
      int n = seq0 + tid;
      out[6144 + n] = grp_lds[tid][0] + grp_lds[tid][1] + grp_lds[tid][2];
      out[8192 + n] = grp_lds[tid][4] + grp_lds[tid][5] + grp_lds[tid][6];
    }
  } else {
    // value = tanh(h @ Wmc1^T + bmc1) . Wmc2 + bmc2
    bf16x8 bm1[2];
    #pragma unroll
    for (int kf = 0; kf < 2; ++kf) {
      const float* wp = Wmc1 + (hs0 + c16) * 64 + kf * 32 + q4 * 8;
      bf16x8 bb;
      #pragma unroll
      for (int j = 0; j < 8; ++j) bb[j] = (short)f2bf(wp[j]);
      bm1[kf] = bb;
    }
    float bs = bmc1[hs0 + c16];
    f32x4 acc = {bs, bs, bs, bs};
    acc = __builtin_amdgcn_mfma_f32_16x16x32_bf16(fh0, bm1[0], acc, 0, 0, 0);
    acc = __builtin_amdgcn_mfma_f32_16x16x32_bf16(fh1, bm1[1], acc, 0, 0, 0);
    float wv2 = Wmc2[hs0 + c16];
    float pv[4];
    #pragma unroll
    for (int rr = 0; rr < 4; ++rr) pv[rr] = ftanh(acc[rr]) * wv2;
    #pragma unroll
    for (int rr = 0; rr < 4; ++rr) {
      pv[rr] += __shfl_xor(pv[rr], 1);
      pv[rr] += __shfl_xor(pv[rr], 2);
      pv[rr] += __shfl_xor(pv[rr], 4);
      pv[rr] += __shfl_xor(pv[rr], 8);
    }
    if (c16 == 0) {
      #pragma unroll
      for (int rr = 0; rr < 4; ++rr) val_lds[q4 * 4 + rr][w] = pv[rr];
    }
    __syncthreads();
    if (tid < 16) {
      int n = seq0 + tid;
      out[10240 + n] = val_lds[tid][0] + val_lds[tid][1] + val_lds[tid][2] +
                       val_lds[tid][3] + bmc2[0];
    }
  }
}

extern "C" void kernel_launch(void* const* d_in, const int* in_sizes, int n_in,
                              void* d_out, int out_size, void* d_ws, size_t ws_size,
                              hipStream_t stream) {
  const float* x_actor = (const float*)d_in[0];
  const int* action = (const int*)d_in[2];
  const int* Gmat  = (const int*)d_in[3];
  const float* Wa = (const float*)d_in[4];  const float* ba = (const float*)d_in[5];
  const float* Wg = (const float*)d_in[6];  const float* bg = (const float*)d_in[7];
  const float* Qw = (const float*)d_in[8];  const float* Kw = (const float*)d_in[9];
  const float* W2 = (const float*)d_in[10]; const float* b2 = (const float*)d_in[11];
  const float* Wih_a = (const float*)d_in[12]; const float* Whh_a = (const float*)d_in[13];
  const float* bih_a = (const float*)d_in[14]; const float* bhh_a = (const float*)d_in[15];
  const float* Wih_c = (const float*)d_in[16]; const float* Whh_c = (const float*)d_in[17];
  const float* bih_c = (const float*)d_in[18]; const float* bhh_c = (const float*)d_in[19];
  const float* Wma1 = (const float*)d_in[20]; const float* bma1 = (const float*)d_in[21];
  const float* Wma2 = (const float*)d_in[22]; const float* bma2 = (const float*)d_in[23];
  const float* Wmc1 = (const float*)d_in[24]; const float* bmc1 = (const float*)d_in[25];
  const float* Wmc2 = (const float*)d_in[26]; const float* bmc2 = (const float*)d_in[27];

  unsigned short* us = (unsigned short*)d_ws;
  unsigned short* a_lin_bf = us;                 // 2,097,152
  unsigned short* s_b  = us + 2097152;
  unsigned short* q_b  = us + 4194304;
  unsigned short* k_b  = us + 6291456;
  unsigned short* sT_b = us + 8388608;
  unsigned short* so_b = us + 10485760;
  unsigned short* Wfold_b = us + 12582912;       // 32,768
  float* fb = (float*)(us + 12615680);
  float* bias_fold = fb;                         // 256
  unsigned* gmask = (unsigned*)(fb + 256);       // 2,048
  float* out = (float*)d_out;

  kA_lin<<<2048, 256, 0, stream>>>(x_actor, Wa, ba, Wg, bg, Qw, Kw,
                                   Gmat, Wih_c, W2, b2,
                                   a_lin_bf, s_b, q_b, k_b, sT_b, Wfold_b,
                                   bias_fold, gmask);
  kB_attn<<<512, 512, 0, stream>>>(q_b, k_b, sT_b, gmask, so_b);
  kR_lstm<<<256, 256, 0, stream>>>(a_lin_bf, s_b, so_b, Wfold_b, bias_fold,
                                   Wih_a, Whh_a, Whh_c, bih_a, bhh_a, bih_c, bhh_c,
                                   action, Wma1, bma1, Wma2, bma2,
                                   Wmc1, bmc1, Wmc2, bmc2, out);
}

// Round 6
// 77.647 us; speedup vs baseline: 8.7646x; 1.0227x over previous
//
#include <hip/hip_runtime.h>
#include <math.h>

#define B_ 8
#define L_ 16
#define M_ 256
#define H_ 53
#define HID_ 64
#define LB_ 128  // L_*B_
#define SCALE_ 0.08838834764831845f

typedef __attribute__((ext_vector_type(8))) short bf16x8;
typedef __attribute__((ext_vector_type(4))) float f32x4;

__device__ inline unsigned short f2bf(float f) {
  unsigned u = __builtin_bit_cast(unsigned, f);
  unsigned r = (u + 0x7FFFu + ((u >> 16) & 1u)) >> 16;
  return (unsigned short)r;
}
// fast sigmoid / tanh via hw exp+rcp (rel err ~1e-6, tolerance is 9.75e-2)
__device__ inline float sigm(float x) { return __builtin_amdgcn_rcpf(1.f + __expf(-x)); }
__device__ inline float ftanh(float x) { return 1.f - 2.f * __builtin_amdgcn_rcpf(1.f + __expf(2.f * x)); }

// ---------------- kP: one-time precomputes ----------------
// blocks 0..127: Wfold[256][128]; 128..159: WQ/WK[64][64]; 160: bq/bk;
// 161: bias_fold[256]; 162..225: gmask.
__global__ __launch_bounds__(256) void kP_pre(
    const float* __restrict__ Wg, const float* __restrict__ bg,
    const float* __restrict__ Qw, const float* __restrict__ Kw,
    const float* __restrict__ Wih_c, const float* __restrict__ W2,
    const float* __restrict__ b2, const int* __restrict__ Gmat,
    unsigned short* __restrict__ WQ_b, unsigned short* __restrict__ WK_b,
    float* __restrict__ bqk, unsigned short* __restrict__ Wfold_b,
    float* __restrict__ bias_fold, unsigned* __restrict__ gmask) {
  int blk = blockIdx.x, tid = threadIdx.x;
  if (blk < 128) {
    int idx = blk * 256 + tid;        // n*128 + t
    int n = idx >> 7, t = idx & 127;
    float acc = 0.f;
    for (int e = 0; e < 64; ++e) acc = fmaf(Wih_c[n * 64 + e], W2[e * 128 + t], acc);
    Wfold_b[idx] = f2bf(acc);
  } else if (blk < 160) {
    int idx = (blk - 128) * 256 + tid;  // 8192 entries
    int which = idx >> 12, n = (idx >> 6) & 63, j = idx & 63;
    const float* Mm = which ? Kw : Qw;
    float acc = 0.f;
    if (j < 53) {
      for (int e = 0; e < 64; ++e) acc = fmaf(Mm[e * 64 + n], Wg[e * 53 + j], acc);
      if (which == 0) acc *= SCALE_;
    }
    (which ? WK_b : WQ_b)[n * 64 + j] = f2bf(acc);
  } else if (blk == 160) {
    if (tid < 128) {
      int which = tid >> 6, n = tid & 63;
      const float* Mm = which ? Kw : Qw;
      float acc = 0.f;
      for (int e = 0; e < 64; ++e) acc = fmaf(bg[e], Mm[e * 64 + n], acc);
      if (which == 0) acc *= SCALE_;
      bqk[tid] = acc;
    }
  } else if (blk == 161) {
    float acc = 0.f;
    for (int e = 0; e < 64; ++e) acc = fmaf(Wih_c[tid * 64 + e], b2[e], acc);
    bias_fold[tid] = acc;
  } else {
    int w = tid >> 6, ln = tid & 63;
    int l = (blk - 162) * 4 + w;
    #pragma unroll
    for (int c = 0; c < 4; ++c) {
      int gv = Gmat[l * 256 + c * 64 + ln];
      unsigned long long msk = __ballot(gv > 0);
      if (ln == 0) {
        gmask[l * 8 + c * 2] = (unsigned)msk;
        gmask[l * 8 + c * 2 + 1] = (unsigned)(msk >> 32);
      }
    }
  }
}

// ---------------- Kernel A: MFMA projections  [64 rows] x [256 outs: a|s|q|k] ----------------
#define XS 68
#define WS 68
#define OS 264
__global__ __launch_bounds__(256, 2) void kA_lin(const float* __restrict__ x,
    const float* __restrict__ Wa, const float* __restrict__ ba,
    const float* __restrict__ Wg, const float* __restrict__ bg,
    const unsigned short* __restrict__ WQ_b, const unsigned short* __restrict__ WK_b,
    const float* __restrict__ bqk,
    unsigned short* __restrict__ a_lin_bf, unsigned short* __restrict__ s_b,
    unsigned short* __restrict__ q_b, unsigned short* __restrict__ k_b,
    unsigned short* __restrict__ sT_b) {
  __shared__ __attribute__((aligned(16))) unsigned short x_lds[64 * XS];
  __shared__ __attribute__((aligned(16))) unsigned short w_lds[256 * WS];
  __shared__ float bias_lds[256];
  __shared__ __attribute__((aligned(16))) unsigned short out_lds[64 * OS];
  int tid = threadIdx.x;
  int row0 = blockIdx.x * 64;
  // stage x rows -> bf16 (pad j>=53 with 0)
  for (int i = tid; i < 64 * 64; i += 256) {
    int r = i >> 6, j = i & 63;
    int row = row0 + r;
    int lb = row >> 8, m = row & 255;
    int l = lb >> 3, b = lb & 7;
    float v = (j < 53) ? x[((b * L_ + l) * M_ + m) * H_ + j] : 0.f;
    x_lds[r * XS + j] = f2bf(v);
  }
  // stage weights: rows 0-63 Wa, 64-127 Wg, 128-191 WQ, 192-255 WK
  for (int i = tid; i < 64 * 64; i += 256) {
    int n = i >> 6, j = i & 63;
    w_lds[n * WS + j] = (j < 53) ? f2bf(Wa[n * 53 + j]) : 0;
    w_lds[(64 + n) * WS + j] = (j < 53) ? f2bf(Wg[n * 53 + j]) : 0;
    w_lds[(128 + n) * WS + j] = WQ_b[i];
    w_lds[(192 + n) * WS + j] = WK_b[i];
  }
  {
    float bv;
    if (tid < 64) bv = ba[tid];
    else if (tid < 128) bv = bg[tid - 64];
    else bv = bqk[tid - 128];
    bias_lds[tid] = bv;
  }
  __syncthreads();
  int lane = tid & 63, w = tid >> 6;
  int c16 = lane & 15, q4 = lane >> 4;
  bf16x8 a0 = *(const bf16x8*)&x_lds[(w * 16 + c16) * XS + q4 * 8];
  bf16x8 a1 = *(const bf16x8*)&x_lds[(w * 16 + c16) * XS + 32 + q4 * 8];
  #pragma unroll
  for (int nt = 0; nt < 16; ++nt) {
    bf16x8 b0 = *(const bf16x8*)&w_lds[(nt * 16 + c16) * WS + q4 * 8];
    bf16x8 b1 = *(const bf16x8*)&w_lds[(nt * 16 + c16) * WS + 32 + q4 * 8];
    float bs = bias_lds[nt * 16 + c16];
    f32x4 acc = {bs, bs, bs, bs};
    acc = __builtin_amdgcn_mfma_f32_16x16x32_bf16(a0, b0, acc, 0, 0, 0);
    acc = __builtin_amdgcn_mfma_f32_16x16x32_bf16(a1, b1, acc, 0, 0, 0);
    #pragma unroll
    for (int rr = 0; rr < 4; ++rr)
      out_lds[(w * 16 + q4 * 4 + rr) * OS + nt * 16 + c16] = f2bf(acc[rr]);
  }
  __syncthreads();
  // row-major global writes (uint4 = 8 bf16)
  for (int i = tid; i < 2048; i += 256) {
    int r = i >> 5, seg = i & 31;
    int which = seg >> 3, n8 = (seg & 7) * 8;
    uint4 v = *(const uint4*)&out_lds[r * OS + which * 64 + n8];
    unsigned short* dst = which == 0 ? a_lin_bf : which == 1 ? s_b : which == 2 ? q_b : k_b;
    *(uint4*)&dst[(row0 + r) * 64 + n8] = v;
  }
  // sT: transpose of s cols (64..127)
  int lb = row0 >> 8, m0 = row0 & 255;
  for (int i = tid; i < 1024; i += 256) {
    int e = i >> 4, mc = i & 15;
    ushort4 v;
    v.x = out_lds[(mc * 4 + 0) * OS + 64 + e];
    v.y = out_lds[(mc * 4 + 1) * OS + 64 + e];
    v.z = out_lds[(mc * 4 + 2) * OS + 64 + e];
    v.w = out_lds[(mc * 4 + 3) * OS + 64 + e];
    *(ushort4*)&sT_b[(lb * 64 + e) * 256 + m0 + mc * 4] = v;
  }
}

// ---------------- Kernel B: LDS-free streaming MFMA attention ----------------
__global__ __launch_bounds__(512, 4) void kB_attn(
    const unsigned short* __restrict__ qb, const unsigned short* __restrict__ kb,
    const unsigned short* __restrict__ sT, const unsigned* __restrict__ gmask,
    unsigned short* __restrict__ so_b) {
  int blk = blockIdx.x;
  int lb = blk >> 2;
  int l0 = (blk & 3) << 6;
  int tid = threadIdx.x;
  int lane = tid & 63, w = tid >> 6;
  int c16 = lane & 15, q4 = lane >> 4;
  int lrow0 = (w >> 1) * 16;
  int h0 = (w & 1) * 2;
  int lrow = lb * 256 + l0 + lrow0;
  int kbase = lb * 256;
  const bf16x8 z8 = {0, 0, 0, 0, 0, 0, 0, 0};
  bf16x8 bq[2];
  #pragma unroll
  for (int hp = 0; hp < 2; ++hp) {
    int h = h0 + hp;
    bq[hp] = (q4 < 2) ? *(const bf16x8*)(qb + (lrow + c16) * 64 + h * 16 + q4 * 8) : z8;
  }
  unsigned gwv[8];
  #pragma unroll
  for (int sp = 0; sp < 8; ++sp) gwv[sp] = gmask[(l0 + lrow0 + c16) * 8 + sp];
  f32x4 accO[2];
  float sumh[2];
  #pragma unroll
  for (int hp = 0; hp < 2; ++hp) { accO[hp] = (f32x4){0.f, 0.f, 0.f, 0.f}; sumh[hp] = 0.f; }

  #pragma unroll
  for (int sp = 0; sp < 8; ++sp) {
    unsigned gw = gwv[sp];
    #pragma unroll
    for (int hp = 0; hp < 2; ++hp) {
      int h = h0 + hp;
      unsigned pk0A, pk1A, pk0B, pk1B;
      #pragma unroll
      for (int tp = 0; tp < 2; ++tp) {
        int t = sp * 2 + tp;
        bf16x8 ka = z8;
        if (q4 < 2) ka = *(const bf16x8*)(kb + (kbase + t * 16 + c16) * 64 + h * 16 + q4 * 8);
        f32x4 d = __builtin_amdgcn_mfma_f32_16x16x32_bf16(ka, bq[hp], (f32x4){0.f, 0.f, 0.f, 0.f}, 0, 0, 0);
        int bitbase = tp * 16 + q4 * 4;
        float p0 = ((gw >> (bitbase + 0)) & 1u) ? __expf(d[0]) : 0.f;
        float p1 = ((gw >> (bitbase + 1)) & 1u) ? __expf(d[1]) : 0.f;
        float p2 = ((gw >> (bitbase + 2)) & 1u) ? __expf(d[2]) : 0.f;
        float p3 = ((gw >> (bitbase + 3)) & 1u) ? __expf(d[3]) : 0.f;
        sumh[hp] += (p0 + p1) + (p2 + p3);
        unsigned lo = (unsigned)f2bf(p0) | ((unsigned)f2bf(p1) << 16);
        unsigned hi = (unsigned)f2bf(p2) | ((unsigned)f2bf(p3) << 16);
        if (tp == 0) { pk0A = lo; pk1A = hi; } else { pk0B = lo; pk1B = hi; }
      }
      int srcA = ((q4 & 1) * 2) * 16 + c16, srcB = srcA + 16;
      unsigned g0A = (unsigned)__shfl((int)pk0A, srcA);
      unsigned g1A = (unsigned)__shfl((int)pk1A, srcA);
      unsigned g2A = (unsigned)__shfl((int)pk0A, srcB);
      unsigned g3A = (unsigned)__shfl((int)pk1A, srcB);
      unsigned g0B = (unsigned)__shfl((int)pk0B, srcA);
      unsigned g1B = (unsigned)__shfl((int)pk1B, srcA);
      unsigned g2B = (unsigned)__shfl((int)pk0B, srcB);
      unsigned g3B = (unsigned)__shfl((int)pk1B, srcB);
      bool useB = (q4 >= 2);
      uint4 av;
      av.x = useB ? g0B : g0A;
      av.y = useB ? g1B : g1A;
      av.z = useB ? g2B : g2A;
      av.w = useB ? g3B : g3A;
      bf16x8 af = __builtin_bit_cast(bf16x8, av);
      bf16x8 bs = *(const bf16x8*)(sT + (lb * 64 + h * 16 + c16) * 256 + sp * 32 + q4 * 8);
      accO[hp] = __builtin_amdgcn_mfma_f32_16x16x32_bf16(af, bs, accO[hp], 0, 0, 0);
    }
  }
  #pragma unroll
  for (int hp = 0; hp < 2; ++hp) {
    int h = h0 + hp;
    float s = sumh[hp];
    s += __shfl_xor(s, 16);
    s += __shfl_xor(s, 32);
    #pragma unroll
    for (int r = 0; r < 4; ++r) {
      float sv = __shfl(s, q4 * 4 + r);
      float o = accO[hp][r] / sv;
      so_b[(lb * 256 + l0 + lrow0 + q4 * 4 + r) * 64 + h * 16 + c16] = f2bf(o);
    }
  }
}

// ---------------- kR: LSTM recurrence (1 barrier/step) + fused heads ----------------
__global__ __launch_bounds__(256, 1) void kR_lstm(
    const unsigned short* __restrict__ a_lin_bf,
    const unsigned short* __restrict__ s_b, const unsigned short* __restrict__ so_b,
    const unsigned short* __restrict__ Wfold_b, const float* __restrict__ bias_fold,
    const float* __restrict__ Wih_a,
    const float* __restrict__ Whh_a, const float* __restrict__ Whh_c,
    const float* __restrict__ bih_a, const float* __restrict__ bhh_a,
    const float* __restrict__ bih_c, const float* __restrict__ bhh_c,
    const int* __restrict__ action,
    const float* __restrict__ Wma1, const float* __restrict__ bma1,
    const float* __restrict__ Wma2, const float* __restrict__ bma2,
    const float* __restrict__ Wmc1, const float* __restrict__ bmc1,
    const float* __restrict__ Wmc2, const float* __restrict__ bmc2,
    float* __restrict__ out) {
  int blk = blockIdx.x;
  int which = blk >> 7, g = blk & 127;
  int seq0 = g * 16;
  int b = seq0 >> 8, m0 = seq0 & 255;
  __shared__ __attribute__((aligned(16))) unsigned short h_lds[2][16][72];
  __shared__ __attribute__((aligned(16))) unsigned short ha_lds[16][72];
  __shared__ float logit_lds[16][16];
  __shared__ float grp_lds[16][8];
  __shared__ float val_lds[16][4];
  int tid = threadIdx.x;
  int lane = tid & 63, w = tid >> 6;
  int c16 = lane & 15, q4 = lane >> 4;
  int hs0 = w * 16;
  const float* Whh = which ? Whh_c : Whh_a;
  const float* bih = which ? bih_c : bih_a;
  const float* bhh = which ? bhh_c : bhh_a;
  bf16x8 bwhh[4][2];
  float bias[4];
  #pragma unroll
  for (int nt = 0; nt < 4; ++nt) {
    int n = nt * 64 + hs0 + c16;
    bias[nt] = bih[n] + bhh[n] + (which ? bias_fold[n] : 0.f);
    #pragma unroll
    for (int kf = 0; kf < 2; ++kf) {
      const float* wp = Whh + n * 64 + kf * 32 + q4 * 8;
      bf16x8 bb;
      #pragma unroll
      for (int j = 0; j < 8; ++j) bb[j] = (short)f2bf(wp[j]);
      bwhh[nt][kf] = bb;
    }
  }
  for (int i = tid; i < 576; i += 256) ((unsigned*)h_lds)[i] = 0u;
  float cr[4] = {0.f, 0.f, 0.f, 0.f};
  const int STEP = 2048 * 64;
  __syncthreads();
  int cur = 0;
  if (which == 0) {
    bf16x8 bwin[4][2];
    #pragma unroll
    for (int nt = 0; nt < 4; ++nt) {
      int n = nt * 64 + hs0 + c16;
      #pragma unroll
      for (int kf = 0; kf < 2; ++kf) {
        const float* wp = Wih_a + n * 64 + kf * 32 + q4 * 8;
        bf16x8 bb;
        #pragma unroll
        for (int j = 0; j < 8; ++j) bb[j] = (short)f2bf(wp[j]);
        bwin[nt][kf] = bb;
      }
    }
    const unsigned short* inb = a_lin_bf + (b * 256 + m0 + c16) * 64;
    bf16x8 i0c = *(const bf16x8*)(inb + q4 * 8);
    bf16x8 i1c = *(const bf16x8*)(inb + 32 + q4 * 8);
    for (int l = 0; l < L_; ++l) {
      bf16x8 i0n = i0c, i1n = i1c;
      if (l < L_ - 1) {
        i0n = *(const bf16x8*)(inb + (l + 1) * STEP + q4 * 8);
        i1n = *(const bf16x8*)(inb + (l + 1) * STEP + 32 + q4 * 8);
      }
      bf16x8 ah0 = *(const bf16x8*)&h_lds[cur][c16][q4 * 8];
      bf16x8 ah1 = *(const bf16x8*)&h_lds[cur][c16][32 + q4 * 8];
      f32x4 acc[4];
      #pragma unroll
      for (int nt = 0; nt < 4; ++nt) {
        f32x4 a = {bias[nt], bias[nt], bias[nt], bias[nt]};
        a = __builtin_amdgcn_mfma_f32_16x16x32_bf16(i0c, bwin[nt][0], a, 0, 0, 0);
        a = __builtin_amdgcn_mfma_f32_16x16x32_bf16(i1c, bwin[nt][1], a, 0, 0, 0);
        a = __builtin_amdgcn_mfma_f32_16x16x32_bf16(ah0, bwhh[nt][0], a, 0, 0, 0);
        a = __builtin_amdgcn_mfma_f32_16x16x32_bf16(ah1, bwhh[nt][1], a, 0, 0, 0);
        acc[nt] = a;
      }
      #pragma unroll
      for (int rr = 0; rr < 4; ++rr) {
        float si = sigm(acc[0][rr]);
        float sf = sigm(acc[1][rr]);
        float gg = ftanh(acc[2][rr]);
        float so_ = sigm(acc[3][rr]);
        cr[rr] = sf * cr[rr] + si * gg;
        float hvv = so_ * ftanh(cr[rr]);
        h_lds[cur ^ 1][q4 * 4 + rr][hs0 + c16] = f2bf(hvv);
      }
      __syncthreads();
      cur ^= 1;
      i0c = i0n; i1c = i1n;
    }
  } else {
    bf16x8 bwf[4][4];
    #pragma unroll
    for (int nt = 0; nt < 4; ++nt) {
      int n = nt * 64 + hs0 + c16;
      #pragma unroll
      for (int kc = 0; kc < 4; ++kc) {
        bwf[nt][kc] = *(const bf16x8*)(Wfold_b + n * 128 + kc * 32 + q4 * 8);
      }
    }
    const unsigned short* sbB = s_b + (b * 256 + m0 + c16) * 64;
    const unsigned short* soB = so_b + (b * 256 + m0 + c16) * 64;
    bf16x8 s0c = *(const bf16x8*)(sbB + q4 * 8);
    bf16x8 s1c = *(const bf16x8*)(sbB + 32 + q4 * 8);
    bf16x8 o0c = *(const bf16x8*)(soB + q4 * 8);
    bf16x8 o1c = *(const bf16x8*)(soB + 32 + q4 * 8);
    for (int l = 0; l < L_; ++l) {
      bf16x8 s0n = s0c, s1n = s1c, o0n = o0c, o1n = o1c;
      if (l < L_ - 1) {
        s0n = *(const bf16x8*)(sbB + (l + 1) * STEP + q4 * 8);
        s1n = *(const bf16x8*)(sbB + (l + 1) * STEP + 32 + q4 * 8);
        o0n = *(const bf16x8*)(soB + (l + 1) * STEP + q4 * 8);
        o1n = *(const bf16x8*)(soB + (l + 1) * STEP + 32 + q4 * 8);
      }
      bf16x8 ah0 = *(const bf16x8*)&h_lds[cur][c16][q4 * 8];
      bf16x8 ah1 = *(const bf16x8*)&h_lds[cur][c16][32 + q4 * 8];
      f32x4 acc[4];
      #pragma unroll
      for (int nt = 0; nt < 4; ++nt) {
        f32x4 a = {bias[nt], bias[nt], bias[nt], bias[nt]};
        a = __builtin_amdgcn_mfma_f32_16x16x32_bf16(s0c, bwf[nt][0], a, 0, 0, 0);
        a = __builtin_amdgcn_mfma_f32_16x16x32_bf16(s1c, bwf[nt][1], a, 0, 0, 0);
        a = __builtin_amdgcn_mfma_f32_16x16x32_bf16(o0c, bwf[nt][2], a, 0, 0, 0);
        a = __builtin_amdgcn_mfma_f32_16x16x32_bf16(o1c, bwf[nt][3], a, 0, 0, 0);
        a = __builtin_amdgcn_mfma_f32_16x16x32_bf16(ah0, bwhh[nt][0], a, 0, 0, 0);
        a = __builtin_amdgcn_mfma_f32_16x16x32_bf16(ah1, bwhh[nt][1], a, 0, 0, 0);
        acc[nt] = a;
      }
      #pragma unroll
      for (int rr = 0; rr < 4; ++rr) {
        float si = sigm(acc[0][rr]);
        float sf = sigm(acc[1][rr]);
        float gg = ftanh(acc[2][rr]);
        float so_ = sigm(acc[3][rr]);
        cr[rr] = sf * cr[rr] + si * gg;
        float hvv = so_ * ftanh(cr[rr]);
        h_lds[cur ^ 1][q4 * 4 + rr][hs0 + c16] = f2bf(hvv);
      }
      __syncthreads();
      cur ^= 1;
      s0c = s0n; s1c = s1n; o0c = o0n; o1c = o1n;
    }
  }
  // ---- fused heads ----
  bf16x8 fh0 = *(const bf16x8*)&h_lds[cur][c16][q4 * 8];
  bf16x8 fh1 = *(const bf16x8*)&h_lds[cur][c16][32 + q4 * 8];
  if (which == 0) {
    bf16x8 bm1[2];
    #pragma unroll
    for (int kf = 0; kf < 2; ++kf) {
      const float* wp = Wma1 + (hs0 + c16) * 64 + kf * 32 + q4 * 8;
      bf16x8 bb;
      #pragma unroll
      for (int j = 0; j < 8; ++j) bb[j] = (short)f2bf(wp[j]);
      bm1[kf] = bb;
    }
    float bs = bma1[hs0 + c16];
    f32x4 acc = {bs, bs, bs, bs};
    acc = __builtin_amdgcn_mfma_f32_16x16x32_bf16(fh0, bm1[0], acc, 0, 0, 0);
    acc = __builtin_amdgcn_mfma_f32_16x16x32_bf16(fh1, bm1[1], acc, 0, 0, 0);
    #pragma unroll
    for (int rr = 0; rr < 4; ++rr)
      ha_lds[q4 * 4 + rr][hs0 + c16] = f2bf(ftanh(acc[rr]));
    __syncthreads();
    if (w == 0) {
      bf16x8 af0 = *(const bf16x8*)&ha_lds[c16][q4 * 8];
      bf16x8 af1 = *(const bf16x8*)&ha_lds[c16][32 + q4 * 8];
      const bf16x8 z8 = {0, 0, 0, 0, 0, 0, 0, 0};
      bf16x8 bw2[2] = {z8, z8};
      float bs2 = 0.f;
      if (c16 < 15) {
        #pragma unroll
        for (int kf = 0; kf < 2; ++kf) {
          const float* wp = Wma2 + c16 * 64 + kf * 32 + q4 * 8;
          bf16x8 bb;
          #pragma unroll
          for (int j = 0; j < 8; ++j) bb[j] = (short)f2bf(wp[j]);
          bw2[kf] = bb;
        }
        bs2 = bma2[c16];
      }
      f32x4 acc2 = {bs2, bs2, bs2, bs2};
      acc2 = __builtin_amdgcn_mfma_f32_16x16x32_bf16(af0, bw2[0], acc2, 0, 0, 0);
      acc2 = __builtin_amdgcn_mfma_f32_16x16x32_bf16(af1, bw2[1], acc2, 0, 0, 0);
      #pragma unroll
      for (int rr = 0; rr < 4; ++rr)
        logit_lds[q4 * 4 + rr][c16] = acc2[rr];
    }
    __syncthreads();
    if (tid < 48) {
      int useq = tid & 15, t = tid >> 4;
      int n = seq0 + useq;
      float l0 = logit_lds[useq][t * 5 + 0], l1 = logit_lds[useq][t * 5 + 1];
      float l2 = logit_lds[useq][t * 5 + 2], l3 = logit_lds[useq][t * 5 + 3];
      float l4 = logit_lds[useq][t * 5 + 4];
      float mx = fmaxf(fmaxf(fmaxf(l0, l1), fmaxf(l2, l3)), l4);
      float sm = __expf(l0 - mx) + __expf(l1 - mx) + __expf(l2 - mx) +
                 __expf(l3 - mx) + __expf(l4 - mx);
      float lse = __logf(sm) + mx;
      int a = action[n * 3 + t];
      float lp0 = l0 - lse, lp1 = l1 - lse, lp2 = l2 - lse, lp3 = l3 - lse, lp4 = l4 - lse;
      float lpsel = logit_lds[useq][t * 5 + a] - lse;
      float ent = -(__expf(lp0) * lp0 + __expf(lp1) * lp1 + __expf(lp2) * lp2 +
                    __expf(lp3) * lp3 + __expf(lp4) * lp4);
      grp_lds[useq][t] = lpsel;
      grp_lds[useq][4 + t] = ent;
      out[n * 3 + t] = (float)a;
    }
    __syncthreads();
    if (tid < 16) {
      int n = seq0 + tid;
      out[6144 + n] = grp_lds[tid][0] + grp_lds[tid][1] + grp_lds[tid][2];
      out[8192 + n] = grp_lds[tid][4] + grp_lds[tid][5] + grp_lds[tid][6];
    }
  } else {
    bf16x8 bm1[2];
    #pragma unroll
    for (int kf = 0; kf < 2; ++kf) {
      const float* wp = Wmc1 + (hs0 + c16) * 64 + kf * 32 + q4 * 8;
      bf16x8 bb;
      #pragma unroll
      for (int j = 0; j < 8; ++j) bb[j] = (short)f2bf(wp[j]);
      bm1[kf] = bb;
    }
    float bs = bmc1[hs0 + c16];
    f32x4 acc = {bs, bs, bs, bs};
    acc = __builtin_amdgcn_mfma_f32_16x16x32_bf16(fh0, bm1[0], acc, 0, 0, 0);
    acc = __builtin_amdgcn_mfma_f32_16x16x32_bf16(fh1, bm1[1], acc, 0, 0, 0);
    float wv2 = Wmc2[hs0 + c16];
    float pv[4];
    #pragma unroll
    for (int rr = 0; rr < 4; ++rr) pv[rr] = ftanh(acc[rr]) * wv2;
    #pragma unroll
    for (int rr = 0; rr < 4; ++rr) {
      pv[rr] += __shfl_xor(pv[rr], 1);
      pv[rr] += __shfl_xor(pv[rr], 2);
      pv[rr] += __shfl_xor(pv[rr], 4);
      pv[rr] += __shfl_xor(pv[rr], 8);
    }
    if (c16 == 0) {
      #pragma unroll
      for (int rr = 0; rr < 4; ++rr) val_lds[q4 * 4 + rr][w] = pv[rr];
    }
    __syncthreads();
    if (tid < 16) {
      int n = seq0 + tid;
      out[10240 + n] = val_lds[tid][0] + val_lds[tid][1] + val_lds[tid][2] +
                       val_lds[tid][3] + bmc2[0];
    }
  }
}

extern "C" void kernel_launch(void* const* d_in, const int* in_sizes, int n_in,
                              void* d_out, int out_size, void* d_ws, size_t ws_size,
                              hipStream_t stream) {
  const float* x_actor = (const float*)d_in[0];
  const int* action = (const int*)d_in[2];
  const int* Gmat  = (const int*)d_in[3];
  const float* Wa = (const float*)d_in[4];  const float* ba = (const float*)d_in[5];
  const float* Wg = (const float*)d_in[6];  const float* bg = (const float*)d_in[7];
  const float* Qw = (const float*)d_in[8];  const float* Kw = (const float*)d_in[9];
  const float* W2 = (const float*)d_in[10]; const float* b2 = (const float*)d_in[11];
  const float* Wih_a = (const float*)d_in[12]; const float* Whh_a = (const float*)d_in[13];
  const float* bih_a = (const float*)d_in[14]; const float* bhh_a = (const float*)d_in[15];
  const float* Wih_c = (const float*)d_in[16]; const float* Whh_c = (const float*)d_in[17];
  const float* bih_c = (const float*)d_in[18]; const float* bhh_c = (const float*)d_in[19];
  const float* Wma1 = (const float*)d_in[20]; const float* bma1 = (const float*)d_in[21];
  const float* Wma2 = (const float*)d_in[22]; const float* bma2 = (const float*)d_in[23];
  const float* Wmc1 = (const float*)d_in[24]; const float* bmc1 = (const float*)d_in[25];
  const float* Wmc2 = (const float*)d_in[26]; const float* bmc2 = (const float*)d_in[27];

  unsigned short* us = (unsigned short*)d_ws;
  unsigned short* a_lin_bf = us;                 // 2,097,152
  unsigned short* s_b  = us + 2097152;
  unsigned short* q_b  = us + 4194304;
  unsigned short* k_b  = us + 6291456;
  unsigned short* sT_b = us + 8388608;
  unsigned short* so_b = us + 10485760;
  unsigned short* Wfold_b = us + 12582912;       // 32,768
  unsigned short* WQ_b = us + 12615680;          // 4,096
  unsigned short* WK_b = us + 12619776;          // 4,096
  float* fb = (float*)(us + 12623872);           // 16B aligned
  float* bias_fold = fb;                         // 256
  float* bqk = fb + 256;                         // 128
  unsigned* gmask = (unsigned*)(fb + 384);       // 2,048
  float* out = (float*)d_out;

  kP_pre<<<226, 256, 0, stream>>>(Wg, bg, Qw, Kw, Wih_c, W2, b2, Gmat,
                                  WQ_b, WK_b, bqk, Wfold_b, bias_fold, gmask);
  kA_lin<<<512, 256, 0, stream>>>(x_actor, Wa, ba, Wg, bg, WQ_b, WK_b, bqk,
                                  a_lin_bf, s_b, q_b, k_b, sT_b);
  kB_attn<<<512, 512, 0, stream>>>(q_b, k_b, sT_b, gmask, so_b);
  kR_lstm<<<256, 256, 0, stream>>>(a_lin_bf, s_b, so_b, Wfold_b, bias_fold,
                                   Wih_a, Whh_a, Whh_c, bih_a, bhh_a, bih_c, bhh_c,
                                   action, Wma1, bma1, Wma2, bma2,
                                   Wmc1, bmc1, Wmc2, bmc2, out);
}